// Round 2
// 2150.456 us; speedup vs baseline: 1.7070x; 1.7070x over previous
//
#include <hip/hip_runtime.h>
#include <hip/hip_bf16.h>

// PrefixBLSTM: diagonal-batched bidirectional prefix LSTM + FC head.
// L=128 tokens, T=127 outputs, E=256, H=512, 4H=2048, V=32000.
// ALL float inputs are FLOAT32 (per reference setup_inputs); output is f32
// (threshold 2.060547e-3 == 0.02 * max|ref| -- the f32 relative path).
// MFMA runs on bf16 copies converted in a prep kernel.
//
// Round-2: Round-0 compute changes + barrier reverted to the harness-proven
// RELEASE-add / ACQUIRE-poll form (Round-1 failed with a container error; the
// relaxed-poll barrier was the only sync-affecting diff, so it is reverted to
// isolate infra-vs-kernel).
//  - lstm_diag: kt-outer loop reuses backward B-frags across both M-halves
//    (halves the 512 KB/step/block Whh_b L2 stream).
//  - forward LSTM gates via bf16 MFMA (M=1 trick) on prep-converted Whh_f
//    (kills the 128 KB/step f32 stream + VALU matvec). hf state is bf16.
//  - gx / gxF loads hoisted above the K-loops (overlap MFMA issue).
//  - fc_small re-tiled as grid-stride over 64-col tiles: rows 0..2 use
//    125 blocks (was 32), row-126 cleanup uses all 4 waves.
//
// d_ws unused. All scratch lives in d_out (127*32000 f32 = 16,256,000 B):
//   [0,       131072)  hfO   : hf rows 0..127 bf16      (logits rows 0..2)
//   [131072,  262144)  hbO   : hb rows 0..127 bf16
//   [262144,  393216)  hS0   : backward-h double buf A  (zeroed)
//   [393216,  524288)  hS1   : backward-h double buf B  (zeroed)
//   [524288, 1572864)  gxF   : f32 128x2048
//   [1572864,2621440)  gxeB  : f32 128x2048
//   [2621440,2621696)  bar   : grid barrier   (zeroed)
//   [2621696,2623744)  hf0   : bf16 fwd-h ping (zeroed)
//   [2623744,2625792)  hf1   : bf16 fwd-h pong (zeroed)
//   [2625792,3674368)  WihF bf16 2048x256
//   [3674368,4722944)  WihB bf16 2048x256
//   [4722944,6820096)  WhhB bf16 2048x512
//   [6820096,6885632)  embT bf16 128x256 (gathered emb rows)
//   [6885632,8982784)  WhhF bf16 2048x512
//   [16247808,16249856) c2  : staged row-126 [hf|hb]  == r126 cols 29952..30463
//   [16249856,16256000) hole: staged rows 0..2 [hf|hb]== r126 cols 30464..31999
//
// Stream-serialized phases:
//   memset -> prep -> gx_gemm -> lstm_diag (stages hole+c2)
//   -> fc_main   : rows 3..126, skip (r==126 && n>=29952); reads hfO/hbO
//   -> fc_small A: rows 0..2 all n (reads hole; clobbers hfO/hbO region)
//   -> fc_small B: row 126 n in [30464,32000) (reads c2; clobbers hole)
//   -> fc_small C: row 126 n in [29952,30464) (1 block; LDS-stages c2 first)

typedef __hip_bfloat16 bf;
typedef __attribute__((ext_vector_type(8))) short s8b;   // 8 bf16 (MFMA A/B frag)
typedef __attribute__((ext_vector_type(4))) short s4b;   // 4 bf16
typedef __attribute__((ext_vector_type(4))) float f4;    // MFMA C/D frag

#define MFMA16(a, b, c) __builtin_amdgcn_mfma_f32_16x16x32_bf16((a), (b), (c), 0, 0, 0)
#define GRID_LSTM 32

__device__ __forceinline__ float sigm(float x) { return 1.f / (1.f + __expf(-x)); }
__device__ __forceinline__ float tanh_(float x) { return 1.f - 2.f / (__expf(2.f * x) + 1.f); }

__device__ __forceinline__ short f2bs(float f) {   // f32 -> bf16 bits (RNE)
  bf h = __float2bfloat16(f);
  short s;
  __builtin_memcpy(&s, &h, 2);
  return s;
}
__device__ __forceinline__ s8b cvt8(const float* __restrict__ p) {
  float4 v0 = *(const float4*)p;
  float4 v1 = *(const float4*)(p + 4);
  s8b r;
  r[0] = f2bs(v0.x); r[1] = f2bs(v0.y); r[2] = f2bs(v0.z); r[3] = f2bs(v0.w);
  r[4] = f2bs(v1.x); r[5] = f2bs(v1.y); r[6] = f2bs(v1.z); r[7] = f2bs(v1.w);
  return r;
}
__device__ __forceinline__ s4b cvt4(float4 v) {
  s4b r;
  r[0] = f2bs(v.x); r[1] = f2bs(v.y); r[2] = f2bs(v.z); r[3] = f2bs(v.w);
  return r;
}

// ---------------------------------------------------------------------------
// Kernel 0: prep — f32->bf16 conversions + embedding gather.
// ---------------------------------------------------------------------------
__global__ __launch_bounds__(256) void prep(
    const float* __restrict__ Wihf, const float* __restrict__ Wihb,
    const float* __restrict__ Whhb, const float* __restrict__ Whhf,
    const float* __restrict__ emb, const int* __restrict__ x,
    short* __restrict__ wihfB, short* __restrict__ wihbB,
    short* __restrict__ whhbB, short* __restrict__ whhfB,
    short* __restrict__ embT)
{
  const int gid = blockIdx.x * 256 + threadIdx.x;
  const int stride = gridDim.x * 256;
  for (int i = gid; i < 131072; i += stride)       // 2048*256 / 4
    ((s4b*)wihfB)[i] = cvt4(((const float4*)Wihf)[i]);
  for (int i = gid; i < 131072; i += stride)
    ((s4b*)wihbB)[i] = cvt4(((const float4*)Wihb)[i]);
  for (int i = gid; i < 262144; i += stride)       // 2048*512 / 4
    ((s4b*)whhbB)[i] = cvt4(((const float4*)Whhb)[i]);
  for (int i = gid; i < 262144; i += stride)
    ((s4b*)whhfB)[i] = cvt4(((const float4*)Whhf)[i]);
  for (int i = gid; i < 8192; i += stride) {       // 128*256 / 4
    const int t = i >> 6, k = (i & 63) << 2;
    ((s4b*)embT)[i] = cvt4(*(const float4*)(emb + x[t] * 256 + k));
  }
}

// ---------------------------------------------------------------------------
// Kernel 1: gx precompute (both directions). 128x2048, K=256 GEMM each.
// ---------------------------------------------------------------------------
__global__ __launch_bounds__(256) void gx_gemm(
    const short* __restrict__ embT,
    const short* __restrict__ WfB, const short* __restrict__ WbB,
    const float* __restrict__ bif, const float* __restrict__ bhf,
    const float* __restrict__ bib, const float* __restrict__ bhb,
    float* __restrict__ gxF, float* __restrict__ gxeB)
{
  const int tid  = threadIdx.x;
  const int nb   = blockIdx.x & 15;
  const int mat  = blockIdx.x >> 4;
  const short* W = mat ? WbB : WfB;
  const float* bi = mat ? bib : bif;
  const float* bh = mat ? bhb : bhf;
  float* out     = mat ? gxeB : gxF;

  const int wv = tid >> 6, lane = tid & 63, quad = lane >> 4, l16 = lane & 15;
  const int wm = wv >> 1, wn = wv & 1;
  const int m0 = wm * 64;
  const int n0 = nb * 128 + wn * 64;

  f4 acc[4][4];
  #pragma unroll
  for (int i = 0; i < 4; ++i)
    #pragma unroll
    for (int j = 0; j < 4; ++j) { acc[i][j][0]=0.f; acc[i][j][1]=0.f; acc[i][j][2]=0.f; acc[i][j][3]=0.f; }

  #pragma unroll
  for (int kt = 0; kt < 8; ++kt) {
    const int k = kt * 32 + quad * 8;
    s8b a[4], bb[4];
    #pragma unroll
    for (int mt = 0; mt < 4; ++mt) a[mt]  = *(const s8b*)(embT + (m0 + mt * 16 + l16) * 256 + k);
    #pragma unroll
    for (int nt = 0; nt < 4; ++nt) bb[nt] = *(const s8b*)(W + (n0 + nt * 16 + l16) * 256 + k);
    #pragma unroll
    for (int mt = 0; mt < 4; ++mt)
      #pragma unroll
      for (int nt = 0; nt < 4; ++nt)
        acc[mt][nt] = MFMA16(a[mt], bb[nt], acc[mt][nt]);
  }

  #pragma unroll
  for (int nt = 0; nt < 4; ++nt) {
    const int n = n0 + nt * 16 + l16;
    const float bias = bi[n] + bh[n];
    #pragma unroll
    for (int mt = 0; mt < 4; ++mt)
      #pragma unroll
      for (int r = 0; r < 4; ++r) {
        const int m = m0 + mt * 16 + quad * 4 + r;
        out[m * 2048 + n] = acc[mt][nt][r] + bias;
      }
  }
}

// ---------------------------------------------------------------------------
// Kernel 2: persistent diagonal LSTM (32 blocks x 256). Block b owns hidden
// units [16b,16b+16) for both directions. One device barrier per step.
// Forward gates via M=1-masked MFMA (wave wv computes gate wv).
// ---------------------------------------------------------------------------
__global__ __launch_bounds__(256) void lstm_diag(
    const short* __restrict__ WhhFb, const short* __restrict__ WhhB,
    const float* __restrict__ gxF, const float* __restrict__ gxeB,
    bf* __restrict__ hS0, bf* __restrict__ hS1,
    bf* __restrict__ hf0, bf* __restrict__ hf1,
    bf* __restrict__ hfOut, bf* __restrict__ hbOut,
    bf* __restrict__ hole, bf* __restrict__ c2,
    int* __restrict__ bar)
{
  const int tid  = threadIdx.x;
  const int blk  = blockIdx.x;
  const int u0   = blk << 4;
  const int wv   = tid >> 6;
  const int lane = tid & 63;
  const int quad = lane >> 4;
  const int l16  = lane & 15;

  __shared__ bf    hfL[512];
  __shared__ float gatesF[64];
  __shared__ float cFs[16];
  if (tid < 16) cFs[tid] = 0.f;

  float cB[8];
  #pragma unroll
  for (int i = 0; i < 8; ++i) cB[i] = 0.f;

  const int mbase0 = wv << 5;
  // s-invariant weight pointers (bf16 rows of 512, +quad k-chunk)
  const short* bF = WhhFb + (((wv << 9) + u0 + l16) << 9) + (quad << 3); // fwd: gate=wv, unit=l16
  const short* bP = WhhB  + ((u0 + l16) << 9) + (quad << 3);             // bwd: unit=l16, gates at +g<<18

  for (int s = 0; s < 127; ++s) {
    const bf* hRd  = (s & 1) ? hS0 : hS1;
    bf*       hWr  = (s & 1) ? hS1 : hS0;
    const bf* hfRd = (s & 1) ? hf0 : hf1;
    bf*       hfWr = (s & 1) ? hf1 : hf0;

    // stage forward h into LDS (256 threads x 4B = 1024B)
    ((uint*)hfL)[tid] = ((const uint*)hfRd)[tid];

    // prefetch gx operands (independent of h -> overlaps everything)
    const bool act1 = (mbase0 + 31 >= s);
    const bool act0 = (mbase0 + 15 >= s);
    float g4[2][4][4];
    #pragma unroll
    for (int h = 0; h < 2; ++h) {
      const int mb = mbase0 + (h << 4);
      #pragma unroll
      for (int r = 0; r < 4; ++r) {
        const int m = mb + (quad << 2) + r;
        if (m >= s && m <= 126) {
          const float* gx = gxeB + (m - s) * 2048 + u0 + l16;
          g4[h][r][0] = gx[0];
          g4[h][r][1] = gx[512];
          g4[h][r][2] = gx[1024];
          g4[h][r][3] = gx[1536];
        }
      }
    }
    const float gxf = gxF[s * 2048 + (wv << 9) + u0 + l16];

    __syncthreads();   // hfL ready

    // ---- forward: gates(gate=wv, units u0..u0+15) via M=1 MFMA ----
    {
      f4 accF; accF[0] = 0.f; accF[1] = 0.f; accF[2] = 0.f; accF[3] = 0.f;
      const s8b z = {0, 0, 0, 0, 0, 0, 0, 0};
      #pragma unroll
      for (int kt = 0; kt < 16; ++kt) {
        const int ko = kt << 5;
        const s8b h8 = *(const s8b*)((const short*)hfL + ko + (quad << 3));
        const s8b a  = (l16 == 0) ? h8 : z;      // A row 0 = hf, rows 1..15 = 0
        const s8b b  = *(const s8b*)(bF + ko);
        accF = MFMA16(a, b, accF);
      }
      if (lane < 16) gatesF[(wv << 4) + lane] = accF[0] + gxf;  // C row0 = quad0,reg0
    }

    // ---- backward batched GEMM: rows [mbase0, mbase0+32), B-frags shared ----
    if (act1) {
      f4 acc[2][4];
      #pragma unroll
      for (int h = 0; h < 2; ++h)
        #pragma unroll
        for (int g = 0; g < 4; ++g) { acc[h][g][0]=0.f; acc[h][g][1]=0.f; acc[h][g][2]=0.f; acc[h][g][3]=0.f; }
      const bf* aP0 = hRd + ((mbase0 + l16) << 9) + (quad << 3);
      #pragma unroll
      for (int kt = 0; kt < 16; ++kt) {
        const int ko = kt << 5;
        const s8b b0 = *(const s8b*)(bP + ko);
        const s8b b1 = *(const s8b*)(bP + (1 << 18) + ko);
        const s8b b2 = *(const s8b*)(bP + (2 << 18) + ko);
        const s8b b3 = *(const s8b*)(bP + (3 << 18) + ko);
        const s8b a1 = *(const s8b*)(aP0 + (16 << 9) + ko);
        if (act0) {
          const s8b a0 = *(const s8b*)(aP0 + ko);
          acc[0][0] = MFMA16(a0, b0, acc[0][0]);
          acc[0][1] = MFMA16(a0, b1, acc[0][1]);
          acc[0][2] = MFMA16(a0, b2, acc[0][2]);
          acc[0][3] = MFMA16(a0, b3, acc[0][3]);
        }
        acc[1][0] = MFMA16(a1, b0, acc[1][0]);
        acc[1][1] = MFMA16(a1, b1, acc[1][1]);
        acc[1][2] = MFMA16(a1, b2, acc[1][2]);
        acc[1][3] = MFMA16(a1, b3, acc[1][3]);
      }
      #pragma unroll
      for (int h = 0; h < 2; ++h) {
        if (h == 0 && !act0) continue;
        const int mb = mbase0 + (h << 4);
        #pragma unroll
        for (int r = 0; r < 4; ++r) {
          const int m = mb + (quad << 2) + r;
          if (m >= s && m <= 126) {
            const float gi = acc[h][0][r] + g4[h][r][0];
            const float gf = acc[h][1][r] + g4[h][r][1];
            const float gg = acc[h][2][r] + g4[h][r][2];
            const float go = acc[h][3][r] + g4[h][r][3];
            const float ii = sigm(gi), ff = sigm(gf);
            const float g2 = tanh_(gg), oo = sigm(go);
            const int ci = (h << 2) + r;
            const float cn = ff * cB[ci] + ii * g2;
            cB[ci] = cn;
            const bf hn = __float2bfloat16(oo * tanh_(cn));
            const int idx = (m << 9) + u0 + l16;
            if (m > s) hWr[idx] = hn;
            else       hbOut[idx] = hn;                // m == s: finalized
          }
        }
      }
    }

    __syncthreads();   // gatesF ready
    if (tid < 16) {
      const float gi = gatesF[tid], gf = gatesF[16 + tid];
      const float gg = gatesF[32 + tid], go = gatesF[48 + tid];
      const float ii = sigm(gi), ff = sigm(gf), g2 = tanh_(gg), oo = sigm(go);
      const float cn = ff * cFs[tid] + ii * g2;
      cFs[tid] = cn;
      const bf h16 = __float2bfloat16(oo * tanh_(cn));
      hfWr[u0 + tid] = h16;
      hfOut[(s << 9) + u0 + tid] = h16;
    }

    // ---- grid barrier (monotone counter, agent scope) — harness-proven form
    __syncthreads();
    if (tid == 0) {
      __threadfence();
      __hip_atomic_fetch_add(bar, 1, __ATOMIC_RELEASE, __HIP_MEMORY_SCOPE_AGENT);
      const int target = (s + 1) * GRID_LSTM;
      while (__hip_atomic_load(bar, __ATOMIC_ACQUIRE, __HIP_MEMORY_SCOPE_AGENT) < target) {
        __builtin_amdgcn_s_sleep(1);
      }
    }
    __syncthreads();
  }

  // ---- stage relay data (all writes barrier-visible) ----
  if (blk == 0) {   // hole: rows 0..2, per-row [hf(512)|hb(512)]
    for (int i = tid; i < 3 * 1024; i += 256) {
      const int r = i >> 10, k = i & 1023;
      hole[i] = (k < 512) ? hfOut[r * 512 + k] : hbOut[r * 512 + (k - 512)];
    }
  }
  if (blk == 1) {   // c2: row 126 [hf(512)|hb(512)]
    for (int i = tid; i < 1024; i += 256)
      c2[i] = (i < 512) ? hfOut[126 * 512 + i] : hbOut[126 * 512 + (i - 512)];
  }
}

// ---------------------------------------------------------------------------
// Kernel 3: FC main. Rows 3..126 (skip r126 n>=29952). A = hfO/hbO bf16;
// B = fc_w f32 streamed once, converted in-register. Output f32.
// ---------------------------------------------------------------------------
__global__ __launch_bounds__(256) void fc_main(
    const bf* __restrict__ hfOut, const bf* __restrict__ hbOut,
    const float* __restrict__ fcw, const float* __restrict__ fcb,
    float* __restrict__ out)
{
  const int tid = threadIdx.x;
  const int wv = tid >> 6, lane = tid & 63, quad = lane >> 4, l16 = lane & 15;
  const int wm = wv >> 1, wn = wv & 1;
  const int m0 = wm * 64;
  const int n0 = blockIdx.x * 128 + wn * 64;

  f4 acc[4][4];
  #pragma unroll
  for (int i = 0; i < 4; ++i)
    #pragma unroll
    for (int j = 0; j < 4; ++j) { acc[i][j][0]=0.f; acc[i][j][1]=0.f; acc[i][j][2]=0.f; acc[i][j][3]=0.f; }

  #pragma unroll
  for (int half = 0; half < 2; ++half) {
    const bf* A = half ? hbOut : hfOut;
    #pragma unroll
    for (int kt = 0; kt < 16; ++kt) {
      const int k = kt * 32 + quad * 8;
      s8b a[4], b[4];
      #pragma unroll
      for (int mt = 0; mt < 4; ++mt) a[mt] = *(const s8b*)(A + (m0 + mt * 16 + l16) * 512 + k);
      #pragma unroll
      for (int nt = 0; nt < 4; ++nt) b[nt] = cvt8(fcw + (n0 + nt * 16 + l16) * 1024 + half * 512 + k);
      #pragma unroll
      for (int mt = 0; mt < 4; ++mt)
        #pragma unroll
        for (int nt = 0; nt < 4; ++nt)
          acc[mt][nt] = MFMA16(a[mt], b[nt], acc[mt][nt]);
    }
  }

  #pragma unroll
  for (int nt = 0; nt < 4; ++nt) {
    const int n = n0 + nt * 16 + l16;
    const float bb = fcb[n];
    #pragma unroll
    for (int mt = 0; mt < 4; ++mt)
      #pragma unroll
      for (int r = 0; r < 4; ++r) {
        const int m = m0 + mt * 16 + quad * 4 + r;
        if (m >= 3 && m < 127 && !(m == 126 && n >= 29952))
          out[m * 32000 + n] = acc[mt][nt][r] + bb;
      }
  }
}

// ---------------------------------------------------------------------------
// Kernel 4: FC relay. rowCount (<=3) rows from rowBase, cols [nstart,nstart+
// ncols) with ncols a multiple of 64. A rows ([hf|hb], 1024 each) staged from
// `stage` into LDS before any write (so a 1-block launch may overwrite its
// own stage region). Waves grid-stride over 64-col tiles.
// ---------------------------------------------------------------------------
__global__ __launch_bounds__(256) void fc_small(
    const bf* __restrict__ stage,
    const float* __restrict__ fcw, const float* __restrict__ fcb,
    float* __restrict__ out,
    int nstart, int ncols, int rowBase, int rowCount)
{
  __shared__ short As[16 * 1032];
  const int tid = threadIdx.x;
  for (int i = tid; i < 16 * 1032; i += 256) As[i] = 0;
  __syncthreads();
  for (int i = tid; i < rowCount * 1024; i += 256) {
    const int r = i >> 10, k = i & 1023;
    As[r * 1032 + k] = ((const short*)stage)[i];
  }
  __syncthreads();

  const int wv = tid >> 6, lane = tid & 63, quad = lane >> 4, l16 = lane & 15;
  const int nt64 = ncols >> 6;   // 64-col tiles (ncols % 64 == 0)
  for (int tile = blockIdx.x * 4 + wv; tile < nt64; tile += gridDim.x * 4) {
    const int n0 = nstart + (tile << 6);
    f4 acc[4];
    #pragma unroll
    for (int nt = 0; nt < 4; ++nt) { acc[nt][0]=0.f; acc[nt][1]=0.f; acc[nt][2]=0.f; acc[nt][3]=0.f; }
    #pragma unroll
    for (int kt = 0; kt < 32; ++kt) {
      const int k = kt * 32 + quad * 8;
      const s8b a = *(const s8b*)(As + l16 * 1032 + k);
      s8b b[4];
      #pragma unroll
      for (int nt = 0; nt < 4; ++nt) b[nt] = cvt8(fcw + (n0 + nt * 16 + l16) * 1024 + k);
      #pragma unroll
      for (int nt = 0; nt < 4; ++nt) acc[nt] = MFMA16(a, b[nt], acc[nt]);
    }
    #pragma unroll
    for (int nt = 0; nt < 4; ++nt) {
      const int n = n0 + nt * 16 + l16;
      const float bb = fcb[n];
      #pragma unroll
      for (int r = 0; r < 4; ++r) {
        const int m = quad * 4 + r;
        if (m < rowCount)
          out[(rowBase + m) * 32000 + n] = acc[nt][r] + bb;
      }
    }
  }
}

// ---------------------------------------------------------------------------
extern "C" void kernel_launch(void* const* d_in, const int* in_sizes, int n_in,
                              void* d_out, int out_size, void* d_ws, size_t ws_size,
                              hipStream_t stream) {
  const int*   x    = (const int*)d_in[0];
  const float* emb  = (const float*)d_in[1];
  const float* Wihf = (const float*)d_in[2];
  const float* Whhf = (const float*)d_in[3];
  const float* bihf = (const float*)d_in[4];
  const float* bhhf = (const float*)d_in[5];
  const float* Wihb = (const float*)d_in[6];
  const float* Whhb = (const float*)d_in[7];
  const float* bihb = (const float*)d_in[8];
  const float* bhhb = (const float*)d_in[9];
  const float* fcw  = (const float*)d_in[10];
  const float* fcb  = (const float*)d_in[11];
  float* out = (float*)d_out;

  char* S = (char*)d_out;                 // ALL scratch lives in d_out
  bf*    hfO   = (bf*)(S + 0);
  bf*    hbO   = (bf*)(S + 131072);
  bf*    hS0   = (bf*)(S + 262144);
  bf*    hS1   = (bf*)(S + 393216);
  float* gxF   = (float*)(S + 524288);
  float* gxeB  = (float*)(S + 1572864);
  int*   bar   = (int*)(S + 2621440);
  bf*    hfb0  = (bf*)(S + 2621696);
  bf*    hfb1  = (bf*)(S + 2623744);
  short* wihfB = (short*)(S + 2625792);
  short* wihbB = (short*)(S + 3674368);
  short* whhbB = (short*)(S + 4722944);
  short* embT  = (short*)(S + 6820096);
  short* whhfB = (short*)(S + 6885632);
  bf*    c2    = (bf*)(S + 16247808);     // r126 cols 29952..30463
  bf*    hole  = (bf*)(S + 16249856);     // r126 cols 30464..31999

  // zero hS0/hS1 + (gx harmlessly) + bar + hf0/hf1
  hipMemsetAsync(S + 262144, 0, 2625792 - 262144, stream);

  hipLaunchKernelGGL(prep, dim3(256), dim3(256), 0, stream,
                     Wihf, Wihb, Whhb, Whhf, emb, x, wihfB, wihbB, whhbB, whhfB, embT);
  hipLaunchKernelGGL(gx_gemm, dim3(32), dim3(256), 0, stream,
                     embT, wihfB, wihbB, bihf, bhhf, bihb, bhhb, gxF, gxeB);
  hipLaunchKernelGGL(lstm_diag, dim3(GRID_LSTM), dim3(256), 0, stream,
                     whhfB, whhbB, gxF, gxeB, hS0, hS1, hfb0, hfb1, hfO, hbO, hole, c2, bar);
  hipLaunchKernelGGL(fc_main, dim3(250), dim3(256), 0, stream,
                     hfO, hbO, fcw, fcb, out);
  // rows 0..2 (reads hole; clobbers hfO/hbO with final logits) — 500 tiles
  hipLaunchKernelGGL(fc_small, dim3(125), dim3(256), 0, stream,
                     hole, fcw, fcb, out, 0, 32000, 0, 3);
  // row 126 cols 30464..31999 (reads c2; clobbers hole) — 24 tiles
  hipLaunchKernelGGL(fc_small, dim3(6), dim3(256), 0, stream,
                     c2, fcw, fcb, out, 30464, 1536, 126, 1);
  // row 126 cols 29952..30463 (1 block; LDS-stages c2 then overwrites it)
  hipLaunchKernelGGL(fc_small, dim3(1), dim3(256), 0, stream,
                     c2, fcw, fcb, out, 29952, 512, 126, 1);
}

// Round 3
// 1816.003 us; speedup vs baseline: 2.0214x; 1.1842x over previous
//
#include <hip/hip_runtime.h>
#include <hip/hip_bf16.h>

// PrefixBLSTM: diagonal-batched bidirectional prefix LSTM + FC head.
// L=128 tokens, T=127 outputs, E=256, H=512, 4H=2048, V=32000.
// ALL float inputs are FLOAT32 (per reference setup_inputs); output is f32
// (threshold 2.060547e-3 == 0.02 * max|ref| -- the f32 relative path).
// MFMA runs on bf16 copies converted in a prep kernel.
//
// Round-3 (lstm_diag focus; prev best 2150 us, lstm_diag=1661 us @ 13.1 us/step):
//  - DISTRIBUTED-FLAG grid barrier: 32 same-line atomic RMWs (serialized
//    ~300ns each at the coherence point ~ 9.6 us/step) replaced by per-block
//    release-stores to 32 separate 128B lines + parallel acquire-poll by
//    lanes 0..31. Release/fence/acquire semantics preserved exactly.
//  - Backward Whh_b slice held in REGISTERS (64 x s8b = 256 VGPR/wave),
//    loaded once pre-loop; inner kt loop is now A-load + MFMA only.
//    __launch_bounds__(256,1) allows 512 VGPR (occupancy already 1 blk/CU).
//  - gxeB stored gate-interleaved [j][unit][4]: per-step gx prefetch is
//    8x float4 instead of 32 scattered dwords.
//
// d_ws unused. All scratch lives in d_out (127*32000 f32 = 16,256,000 B):
//   [0,       131072)  hfO   : hf rows 0..127 bf16      (logits rows 0..2)
//   [131072,  262144)  hbO   : hb rows 0..127 bf16
//   [262144,  393216)  hS0   : backward-h double buf A  (zeroed)
//   [393216,  524288)  hS1   : backward-h double buf B  (zeroed)
//   [524288, 1572864)  gxF   : f32 128x2048 (linear)
//   [1572864,2621440)  gxeB  : f32 128x512x4 gate-interleaved
//   [2621440,2621696)  (old bar, unused)
//   [2621696,2623744)  hf0   : bf16 fwd-h ping (zeroed)
//   [2623744,2625792)  hf1   : bf16 fwd-h pong (zeroed)
//   [2625792,3674368)  WihF bf16 2048x256
//   [3674368,4722944)  WihB bf16 2048x256
//   [4722944,6820096)  WhhB bf16 2048x512
//   [6820096,6885632)  embT bf16 128x256 (gathered emb rows)
//   [6885632,8982784)  WhhF bf16 2048x512
//   [8982784,8986880)  flags: 32 x 128B barrier flags (zeroed)
//   [16247808,16249856) c2  : staged row-126 [hf|hb]  == r126 cols 29952..30463
//   [16249856,16256000) hole: staged rows 0..2 [hf|hb]== r126 cols 30464..31999
//
// Stream-serialized phases:
//   memset -> prep -> gx_gemm -> lstm_diag (stages hole+c2)
//   -> fc_main   : rows 3..126, skip (r==126 && n>=29952); reads hfO/hbO
//   -> fc_small A: rows 0..2 all n (reads hole; clobbers hfO/hbO region)
//   -> fc_small B: row 126 n in [30464,32000) (reads c2; clobbers hole)
//   -> fc_small C: row 126 n in [29952,30464) (1 block; LDS-stages c2 first)

typedef __hip_bfloat16 bf;
typedef __attribute__((ext_vector_type(8))) short s8b;   // 8 bf16 (MFMA A/B frag)
typedef __attribute__((ext_vector_type(4))) short s4b;   // 4 bf16
typedef __attribute__((ext_vector_type(4))) float f4;    // MFMA C/D frag

#define MFMA16(a, b, c) __builtin_amdgcn_mfma_f32_16x16x32_bf16((a), (b), (c), 0, 0, 0)
#define GRID_LSTM 32

__device__ __forceinline__ float sigm(float x) { return 1.f / (1.f + __expf(-x)); }
__device__ __forceinline__ float tanh_(float x) { return 1.f - 2.f / (__expf(2.f * x) + 1.f); }

__device__ __forceinline__ short f2bs(float f) {   // f32 -> bf16 bits (RNE)
  bf h = __float2bfloat16(f);
  short s;
  __builtin_memcpy(&s, &h, 2);
  return s;
}
__device__ __forceinline__ s8b cvt8(const float* __restrict__ p) {
  float4 v0 = *(const float4*)p;
  float4 v1 = *(const float4*)(p + 4);
  s8b r;
  r[0] = f2bs(v0.x); r[1] = f2bs(v0.y); r[2] = f2bs(v0.z); r[3] = f2bs(v0.w);
  r[4] = f2bs(v1.x); r[5] = f2bs(v1.y); r[6] = f2bs(v1.z); r[7] = f2bs(v1.w);
  return r;
}
__device__ __forceinline__ s4b cvt4(float4 v) {
  s4b r;
  r[0] = f2bs(v.x); r[1] = f2bs(v.y); r[2] = f2bs(v.z); r[3] = f2bs(v.w);
  return r;
}

// ---------------------------------------------------------------------------
// Kernel 0: prep — f32->bf16 conversions + embedding gather.
// ---------------------------------------------------------------------------
__global__ __launch_bounds__(256) void prep(
    const float* __restrict__ Wihf, const float* __restrict__ Wihb,
    const float* __restrict__ Whhb, const float* __restrict__ Whhf,
    const float* __restrict__ emb, const int* __restrict__ x,
    short* __restrict__ wihfB, short* __restrict__ wihbB,
    short* __restrict__ whhbB, short* __restrict__ whhfB,
    short* __restrict__ embT)
{
  const int gid = blockIdx.x * 256 + threadIdx.x;
  const int stride = gridDim.x * 256;
  for (int i = gid; i < 131072; i += stride)       // 2048*256 / 4
    ((s4b*)wihfB)[i] = cvt4(((const float4*)Wihf)[i]);
  for (int i = gid; i < 131072; i += stride)
    ((s4b*)wihbB)[i] = cvt4(((const float4*)Wihb)[i]);
  for (int i = gid; i < 262144; i += stride)       // 2048*512 / 4
    ((s4b*)whhbB)[i] = cvt4(((const float4*)Whhb)[i]);
  for (int i = gid; i < 262144; i += stride)
    ((s4b*)whhfB)[i] = cvt4(((const float4*)Whhf)[i]);
  for (int i = gid; i < 8192; i += stride) {       // 128*256 / 4
    const int t = i >> 6, k = (i & 63) << 2;
    ((s4b*)embT)[i] = cvt4(*(const float4*)(emb + x[t] * 256 + k));
  }
}

// ---------------------------------------------------------------------------
// Kernel 1: gx precompute (both directions). 128x2048, K=256 GEMM each.
// Forward output linear [m][2048]; backward output gate-interleaved
// [m][unit][4] so the LSTM reads one float4 per (m,unit).
// ---------------------------------------------------------------------------
__global__ __launch_bounds__(256) void gx_gemm(
    const short* __restrict__ embT,
    const short* __restrict__ WfB, const short* __restrict__ WbB,
    const float* __restrict__ bif, const float* __restrict__ bhf,
    const float* __restrict__ bib, const float* __restrict__ bhb,
    float* __restrict__ gxF, float* __restrict__ gxeB)
{
  const int tid  = threadIdx.x;
  const int nb   = blockIdx.x & 15;
  const int mat  = blockIdx.x >> 4;
  const short* W = mat ? WbB : WfB;
  const float* bi = mat ? bib : bif;
  const float* bh = mat ? bhb : bhf;
  float* out     = mat ? gxeB : gxF;

  const int wv = tid >> 6, lane = tid & 63, quad = lane >> 4, l16 = lane & 15;
  const int wm = wv >> 1, wn = wv & 1;
  const int m0 = wm * 64;
  const int n0 = nb * 128 + wn * 64;

  f4 acc[4][4];
  #pragma unroll
  for (int i = 0; i < 4; ++i)
    #pragma unroll
    for (int j = 0; j < 4; ++j) { acc[i][j][0]=0.f; acc[i][j][1]=0.f; acc[i][j][2]=0.f; acc[i][j][3]=0.f; }

  #pragma unroll
  for (int kt = 0; kt < 8; ++kt) {
    const int k = kt * 32 + quad * 8;
    s8b a[4], bb[4];
    #pragma unroll
    for (int mt = 0; mt < 4; ++mt) a[mt]  = *(const s8b*)(embT + (m0 + mt * 16 + l16) * 256 + k);
    #pragma unroll
    for (int nt = 0; nt < 4; ++nt) bb[nt] = *(const s8b*)(W + (n0 + nt * 16 + l16) * 256 + k);
    #pragma unroll
    for (int mt = 0; mt < 4; ++mt)
      #pragma unroll
      for (int nt = 0; nt < 4; ++nt)
        acc[mt][nt] = MFMA16(a[mt], bb[nt], acc[mt][nt]);
  }

  #pragma unroll
  for (int nt = 0; nt < 4; ++nt) {
    const int n = n0 + nt * 16 + l16;
    const float bias = bi[n] + bh[n];
    #pragma unroll
    for (int mt = 0; mt < 4; ++mt)
      #pragma unroll
      for (int r = 0; r < 4; ++r) {
        const int m = m0 + mt * 16 + quad * 4 + r;
        if (mat) out[m * 2048 + ((n & 511) << 2) + (n >> 9)] = acc[mt][nt][r] + bias;
        else     out[m * 2048 + n] = acc[mt][nt][r] + bias;
      }
  }
}

// ---------------------------------------------------------------------------
// Kernel 2: persistent diagonal LSTM (32 blocks x 256). Block b owns hidden
// units [16b,16b+16) for both directions. One device barrier per step
// (distributed flags). Backward weights register-resident per wave.
// ---------------------------------------------------------------------------
__global__ __launch_bounds__(256, 1) void lstm_diag(
    const short* __restrict__ WhhFb, const short* __restrict__ WhhB,
    const float* __restrict__ gxF, const float* __restrict__ gxeB,
    bf* __restrict__ hS0, bf* __restrict__ hS1,
    bf* __restrict__ hf0, bf* __restrict__ hf1,
    bf* __restrict__ hfOut, bf* __restrict__ hbOut,
    bf* __restrict__ hole, bf* __restrict__ c2,
    int* __restrict__ flags)
{
  const int tid  = threadIdx.x;
  const int blk  = blockIdx.x;
  const int u0   = blk << 4;
  const int wv   = tid >> 6;
  const int lane = tid & 63;
  const int quad = lane >> 4;
  const int l16  = lane & 15;

  __shared__ bf    hfL[512];
  __shared__ float gatesF[64];
  __shared__ float cFs[16];
  if (tid < 16) cFs[tid] = 0.f;

  float cB[8];
  #pragma unroll
  for (int i = 0; i < 8; ++i) cB[i] = 0.f;

  const int mbase0 = wv << 5;
  // s-invariant weight pointers (bf16 rows of 512, +quad k-chunk)
  const short* bF = WhhFb + (((wv << 9) + u0 + l16) << 9) + (quad << 3); // fwd: gate=wv, unit=l16
  const short* bP = WhhB  + ((u0 + l16) << 9) + (quad << 3);             // bwd: unit=l16, gates at +g<<18

  // ---- preload backward weight slice into registers: wB[gate][kt] ----
  s8b wB[4][16];
  #pragma unroll
  for (int g = 0; g < 4; ++g)
    #pragma unroll
    for (int kt = 0; kt < 16; ++kt)
      wB[g][kt] = *(const s8b*)(bP + (g << 18) + (kt << 5));

  for (int s = 0; s < 127; ++s) {
    const bf* hRd  = (s & 1) ? hS0 : hS1;
    bf*       hWr  = (s & 1) ? hS1 : hS0;
    const bf* hfRd = (s & 1) ? hf0 : hf1;
    bf*       hfWr = (s & 1) ? hf1 : hf0;

    // stage forward h into LDS (256 threads x 4B = 1024B)
    ((uint*)hfL)[tid] = ((const uint*)hfRd)[tid];

    // prefetch gx operands (independent of h -> overlaps everything)
    const bool act1 = (mbase0 + 31 >= s);
    const bool act0 = (mbase0 + 15 >= s);
    float4 g4[2][4];
    #pragma unroll
    for (int h = 0; h < 2; ++h) {
      const int mb = mbase0 + (h << 4);
      #pragma unroll
      for (int r = 0; r < 4; ++r) {
        const int m = mb + (quad << 2) + r;
        if (m >= s && m <= 126)
          g4[h][r] = ((const float4*)gxeB)[((m - s) << 9) + u0 + l16];
      }
    }
    const float gxf = gxF[s * 2048 + (wv << 9) + u0 + l16];

    __syncthreads();   // hfL ready

    // ---- forward: gates(gate=wv, units u0..u0+15) via M=1 MFMA ----
    {
      f4 accF; accF[0] = 0.f; accF[1] = 0.f; accF[2] = 0.f; accF[3] = 0.f;
      const s8b z = {0, 0, 0, 0, 0, 0, 0, 0};
      #pragma unroll
      for (int kt = 0; kt < 16; ++kt) {
        const int ko = kt << 5;
        const s8b h8 = *(const s8b*)((const short*)hfL + ko + (quad << 3));
        const s8b a  = (l16 == 0) ? h8 : z;      // A row 0 = hf, rows 1..15 = 0
        const s8b b  = *(const s8b*)(bF + ko);
        accF = MFMA16(a, b, accF);
      }
      if (lane < 16) gatesF[(wv << 4) + lane] = accF[0] + gxf;  // C row0 = quad0,reg0
    }

    // ---- backward batched GEMM: rows [mbase0, mbase0+32), weights in regs ----
    if (act1) {
      f4 acc[2][4];
      #pragma unroll
      for (int h = 0; h < 2; ++h)
        #pragma unroll
        for (int g = 0; g < 4; ++g) { acc[h][g][0]=0.f; acc[h][g][1]=0.f; acc[h][g][2]=0.f; acc[h][g][3]=0.f; }
      const bf* aP0 = hRd + ((mbase0 + l16) << 9) + (quad << 3);
      #pragma unroll
      for (int kt = 0; kt < 16; ++kt) {
        const int ko = kt << 5;
        const s8b a1 = *(const s8b*)(aP0 + (16 << 9) + ko);
        if (act0) {
          const s8b a0 = *(const s8b*)(aP0 + ko);
          acc[0][0] = MFMA16(a0, wB[0][kt], acc[0][0]);
          acc[0][1] = MFMA16(a0, wB[1][kt], acc[0][1]);
          acc[0][2] = MFMA16(a0, wB[2][kt], acc[0][2]);
          acc[0][3] = MFMA16(a0, wB[3][kt], acc[0][3]);
        }
        acc[1][0] = MFMA16(a1, wB[0][kt], acc[1][0]);
        acc[1][1] = MFMA16(a1, wB[1][kt], acc[1][1]);
        acc[1][2] = MFMA16(a1, wB[2][kt], acc[1][2]);
        acc[1][3] = MFMA16(a1, wB[3][kt], acc[1][3]);
      }
      #pragma unroll
      for (int h = 0; h < 2; ++h) {
        if (h == 0 && !act0) continue;
        const int mb = mbase0 + (h << 4);
        #pragma unroll
        for (int r = 0; r < 4; ++r) {
          const int m = mb + (quad << 2) + r;
          if (m >= s && m <= 126) {
            const float gi = acc[h][0][r] + g4[h][r].x;
            const float gf = acc[h][1][r] + g4[h][r].y;
            const float gg = acc[h][2][r] + g4[h][r].z;
            const float go = acc[h][3][r] + g4[h][r].w;
            const float ii = sigm(gi), ff = sigm(gf);
            const float g2 = tanh_(gg), oo = sigm(go);
            const int ci = (h << 2) + r;
            const float cn = ff * cB[ci] + ii * g2;
            cB[ci] = cn;
            const bf hn = __float2bfloat16(oo * tanh_(cn));
            const int idx = (m << 9) + u0 + l16;
            if (m > s) hWr[idx] = hn;
            else       hbOut[idx] = hn;                // m == s: finalized
          }
        }
      }
    }

    __syncthreads();   // gatesF ready
    if (tid < 16) {
      const float gi = gatesF[tid], gf = gatesF[16 + tid];
      const float gg = gatesF[32 + tid], go = gatesF[48 + tid];
      const float ii = sigm(gi), ff = sigm(gf), g2 = tanh_(gg), oo = sigm(go);
      const float cn = ff * cFs[tid] + ii * g2;
      cFs[tid] = cn;
      const bf h16 = __float2bfloat16(oo * tanh_(cn));
      hfWr[u0 + tid] = h16;
      hfOut[(s << 9) + u0 + tid] = h16;
    }

    // ---- grid barrier: distributed flags (one 128B line per block) ----
    __syncthreads();
    if (tid == 0) {
      __threadfence();   // agent fence: all block stores visible before flag
      __hip_atomic_store(flags + (blk << 5), s + 1, __ATOMIC_RELEASE,
                         __HIP_MEMORY_SCOPE_AGENT);
    }
    if (tid < GRID_LSTM) {
      while (__hip_atomic_load(flags + (tid << 5), __ATOMIC_ACQUIRE,
                               __HIP_MEMORY_SCOPE_AGENT) < s + 1)
        __builtin_amdgcn_s_sleep(1);
    }
    __syncthreads();
  }

  // ---- stage relay data (all writes barrier-visible) ----
  if (blk == 0) {   // hole: rows 0..2, per-row [hf(512)|hb(512)]
    for (int i = tid; i < 3 * 1024; i += 256) {
      const int r = i >> 10, k = i & 1023;
      hole[i] = (k < 512) ? hfOut[r * 512 + k] : hbOut[r * 512 + (k - 512)];
    }
  }
  if (blk == 1) {   // c2: row 126 [hf(512)|hb(512)]
    for (int i = tid; i < 1024; i += 256)
      c2[i] = (i < 512) ? hfOut[126 * 512 + i] : hbOut[126 * 512 + (i - 512)];
  }
}

// ---------------------------------------------------------------------------
// Kernel 3: FC main. Rows 3..126 (skip r126 n>=29952). A = hfO/hbO bf16;
// B = fc_w f32 streamed once, converted in-register. Output f32.
// ---------------------------------------------------------------------------
__global__ __launch_bounds__(256) void fc_main(
    const bf* __restrict__ hfOut, const bf* __restrict__ hbOut,
    const float* __restrict__ fcw, const float* __restrict__ fcb,
    float* __restrict__ out)
{
  const int tid = threadIdx.x;
  const int wv = tid >> 6, lane = tid & 63, quad = lane >> 4, l16 = lane & 15;
  const int wm = wv >> 1, wn = wv & 1;
  const int m0 = wm * 64;
  const int n0 = blockIdx.x * 128 + wn * 64;

  f4 acc[4][4];
  #pragma unroll
  for (int i = 0; i < 4; ++i)
    #pragma unroll
    for (int j = 0; j < 4; ++j) { acc[i][j][0]=0.f; acc[i][j][1]=0.f; acc[i][j][2]=0.f; acc[i][j][3]=0.f; }

  #pragma unroll
  for (int half = 0; half < 2; ++half) {
    const bf* A = half ? hbOut : hfOut;
    #pragma unroll
    for (int kt = 0; kt < 16; ++kt) {
      const int k = kt * 32 + quad * 8;
      s8b a[4], b[4];
      #pragma unroll
      for (int mt = 0; mt < 4; ++mt) a[mt] = *(const s8b*)(A + (m0 + mt * 16 + l16) * 512 + k);
      #pragma unroll
      for (int nt = 0; nt < 4; ++nt) b[nt] = cvt8(fcw + (n0 + nt * 16 + l16) * 1024 + half * 512 + k);
      #pragma unroll
      for (int mt = 0; mt < 4; ++mt)
        #pragma unroll
        for (int nt = 0; nt < 4; ++nt)
          acc[mt][nt] = MFMA16(a[mt], b[nt], acc[mt][nt]);
    }
  }

  #pragma unroll
  for (int nt = 0; nt < 4; ++nt) {
    const int n = n0 + nt * 16 + l16;
    const float bb = fcb[n];
    #pragma unroll
    for (int mt = 0; mt < 4; ++mt)
      #pragma unroll
      for (int r = 0; r < 4; ++r) {
        const int m = m0 + mt * 16 + quad * 4 + r;
        if (m >= 3 && m < 127 && !(m == 126 && n >= 29952))
          out[m * 32000 + n] = acc[mt][nt][r] + bb;
      }
  }
}

// ---------------------------------------------------------------------------
// Kernel 4: FC relay. rowCount (<=3) rows from rowBase, cols [nstart,nstart+
// ncols) with ncols a multiple of 64. A rows ([hf|hb], 1024 each) staged from
// `stage` into LDS before any write (so a 1-block launch may overwrite its
// own stage region). Waves grid-stride over 64-col tiles.
// ---------------------------------------------------------------------------
__global__ __launch_bounds__(256) void fc_small(
    const bf* __restrict__ stage,
    const float* __restrict__ fcw, const float* __restrict__ fcb,
    float* __restrict__ out,
    int nstart, int ncols, int rowBase, int rowCount)
{
  __shared__ short As[16 * 1032];
  const int tid = threadIdx.x;
  for (int i = tid; i < 16 * 1032; i += 256) As[i] = 0;
  __syncthreads();
  for (int i = tid; i < rowCount * 1024; i += 256) {
    const int r = i >> 10, k = i & 1023;
    As[r * 1032 + k] = ((const short*)stage)[i];
  }
  __syncthreads();

  const int wv = tid >> 6, lane = tid & 63, quad = lane >> 4, l16 = lane & 15;
  const int nt64 = ncols >> 6;   // 64-col tiles (ncols % 64 == 0)
  for (int tile = blockIdx.x * 4 + wv; tile < nt64; tile += gridDim.x * 4) {
    const int n0 = nstart + (tile << 6);
    f4 acc[4];
    #pragma unroll
    for (int nt = 0; nt < 4; ++nt) { acc[nt][0]=0.f; acc[nt][1]=0.f; acc[nt][2]=0.f; acc[nt][3]=0.f; }
    #pragma unroll
    for (int kt = 0; kt < 32; ++kt) {
      const int k = kt * 32 + quad * 8;
      const s8b a = *(const s8b*)(As + l16 * 1032 + k);
      s8b b[4];
      #pragma unroll
      for (int nt = 0; nt < 4; ++nt) b[nt] = cvt8(fcw + (n0 + nt * 16 + l16) * 1024 + k);
      #pragma unroll
      for (int nt = 0; nt < 4; ++nt) acc[nt] = MFMA16(a, b[nt], acc[nt]);
    }
    #pragma unroll
    for (int nt = 0; nt < 4; ++nt) {
      const int n = n0 + nt * 16 + l16;
      const float bb = fcb[n];
      #pragma unroll
      for (int r = 0; r < 4; ++r) {
        const int m = quad * 4 + r;
        if (m < rowCount)
          out[(rowBase + m) * 32000 + n] = acc[nt][r] + bb;
      }
    }
  }
}

// ---------------------------------------------------------------------------
extern "C" void kernel_launch(void* const* d_in, const int* in_sizes, int n_in,
                              void* d_out, int out_size, void* d_ws, size_t ws_size,
                              hipStream_t stream) {
  const int*   x    = (const int*)d_in[0];
  const float* emb  = (const float*)d_in[1];
  const float* Wihf = (const float*)d_in[2];
  const float* Whhf = (const float*)d_in[3];
  const float* bihf = (const float*)d_in[4];
  const float* bhhf = (const float*)d_in[5];
  const float* Wihb = (const float*)d_in[6];
  const float* Whhb = (const float*)d_in[7];
  const float* bihb = (const float*)d_in[8];
  const float* bhhb = (const float*)d_in[9];
  const float* fcw  = (const float*)d_in[10];
  const float* fcb  = (const float*)d_in[11];
  float* out = (float*)d_out;

  char* S = (char*)d_out;                 // ALL scratch lives in d_out
  bf*    hfO   = (bf*)(S + 0);
  bf*    hbO   = (bf*)(S + 131072);
  bf*    hS0   = (bf*)(S + 262144);
  bf*    hS1   = (bf*)(S + 393216);
  float* gxF   = (float*)(S + 524288);
  float* gxeB  = (float*)(S + 1572864);
  bf*    hfb0  = (bf*)(S + 2621696);
  bf*    hfb1  = (bf*)(S + 2623744);
  short* wihfB = (short*)(S + 2625792);
  short* wihbB = (short*)(S + 3674368);
  short* whhbB = (short*)(S + 4722944);
  short* embT  = (short*)(S + 6820096);
  short* whhfB = (short*)(S + 6885632);
  int*   flags = (int*)(S + 8982784);     // 32 x 128B
  bf*    c2    = (bf*)(S + 16247808);     // r126 cols 29952..30463
  bf*    hole  = (bf*)(S + 16249856);     // r126 cols 30464..31999

  // zero hS0/hS1 + (gx harmlessly) + old-bar + hf0/hf1, and the flag lines
  hipMemsetAsync(S + 262144, 0, 2625792 - 262144, stream);
  hipMemsetAsync(S + 8982784, 0, 4096, stream);

  hipLaunchKernelGGL(prep, dim3(256), dim3(256), 0, stream,
                     Wihf, Wihb, Whhb, Whhf, emb, x, wihfB, wihbB, whhbB, whhfB, embT);
  hipLaunchKernelGGL(gx_gemm, dim3(32), dim3(256), 0, stream,
                     embT, wihfB, wihbB, bihf, bhhf, bihb, bhhb, gxF, gxeB);
  hipLaunchKernelGGL(lstm_diag, dim3(GRID_LSTM), dim3(256), 0, stream,
                     whhfB, whhbB, gxF, gxeB, hS0, hS1, hfb0, hfb1, hfO, hbO, hole, c2, flags);
  hipLaunchKernelGGL(fc_main, dim3(250), dim3(256), 0, stream,
                     hfO, hbO, fcw, fcb, out);
  // rows 0..2 (reads hole; clobbers hfO/hbO with final logits) — 500 tiles
  hipLaunchKernelGGL(fc_small, dim3(125), dim3(256), 0, stream,
                     hole, fcw, fcb, out, 0, 32000, 0, 3);
  // row 126 cols 30464..31999 (reads c2; clobbers hole) — 24 tiles
  hipLaunchKernelGGL(fc_small, dim3(6), dim3(256), 0, stream,
                     c2, fcw, fcb, out, 30464, 1536, 126, 1);
  // row 126 cols 29952..30463 (1 block; LDS-stages c2 then overwrites it)
  hipLaunchKernelGGL(fc_small, dim3(1), dim3(256), 0, stream,
                     c2, fcw, fcb, out, 29952, 512, 126, 1);
}

// Round 4
// 1582.700 us; speedup vs baseline: 2.3194x; 1.1474x over previous
//
#include <hip/hip_runtime.h>
#include <hip/hip_bf16.h>

// PrefixBLSTM: diagonal-batched bidirectional prefix LSTM + FC head.
// L=128 tokens, T=127 outputs, E=256, H=512, 4H=2048, V=32000.
// ALL float inputs are FLOAT32; output f32 (threshold 2.060547e-3).
//
// Round-4 (prev best 1816 us, lstm_diag=1343 us @ 10.6 us/step):
//  - lstm_diag loop working set made INVALIDATION-IMMUNE: the per-step
//    acquire invalidates the XCD L2, so anything cached was re-streamed
//    from IF$/HBM every step (FETCH 305 KB/step). Now:
//      * backward Whh_b slice -> LDS (64 KB, XOR-swizzle (l16&7)<<4 to fix
//        the 1KB-row-stride 16-way bank conflict on ds_read_b128)
//      * forward Whh_f slice  -> registers (wF[16], only 64 VGPR - small
//        enough to actually stay resident, unlike R3's 256-VGPR attempt)
//      * gxF / gxeB slices    -> LDS (32.5 + 32 KB)
//    LDS total ~132 KB (<160); occupancy already 1 block/CU.
//  - barrier unchanged from proven R3 (distributed flags, release store,
//    ACQUIRE poll).
//  - FC fusion: fc_main computes ALL rows; rows 0..2 held in acc across a
//    one-shot 250-block grid barrier (all hfO/hbO reads done before
//    arrival), then written. Deletes fc_small A/B/C and their second full
//    fc_w stream. fc flags live in row-2 free space (byte 262144+), never
//    touched by pre-barrier stores (m>=3 -> byte>=384000).
//
// Scratch in d_out (16,256,000 B):
//   [0,       131072)  hfO   : hf rows 0..127 bf16
//   [131072,  262144)  hbO   : hb rows 0..127 bf16
//   [262144,  393216)  hS0   : backward-h dbuf A (zeroed) / later fc flags
//   [393216,  524288)  hS1   : backward-h dbuf B (zeroed)
//   [524288, 1572864)  gxF   : f32 128x2048 (linear)
//   [1572864,2621440)  gxeB  : f32 128x512x4 gate-interleaved
//   [2621696,2623744)  hf0   : bf16 fwd-h ping (zeroed)
//   [2623744,2625792)  hf1   : bf16 fwd-h pong (zeroed)
//   [2625792,3674368)  WihF bf16 2048x256
//   [3674368,4722944)  WihB bf16 2048x256
//   [4722944,6820096)  WhhB bf16 2048x512
//   [6820096,6885632)  embT bf16 128x256
//   [6885632,8982784)  WhhF bf16 2048x512
//   [8982784,8986880)  flags: 32 x 128B lstm barrier flags (zeroed)
//
// Phases: memset -> prep -> gx_gemm -> lstm_diag -> memset(fc flags)
//         -> fc_main (all rows; internal grid barrier for rows 0..2)

typedef __hip_bfloat16 bf;
typedef __attribute__((ext_vector_type(8))) short s8b;   // 8 bf16 (MFMA A/B frag)
typedef __attribute__((ext_vector_type(4))) short s4b;   // 4 bf16
typedef __attribute__((ext_vector_type(4))) float f4;    // MFMA C/D frag

#define MFMA16(a, b, c) __builtin_amdgcn_mfma_f32_16x16x32_bf16((a), (b), (c), 0, 0, 0)
#define GRID_LSTM 32
#define GRID_FC   250

__device__ __forceinline__ float sigm(float x) { return 1.f / (1.f + __expf(-x)); }
__device__ __forceinline__ float tanh_(float x) { return 1.f - 2.f / (__expf(2.f * x) + 1.f); }

__device__ __forceinline__ short f2bs(float f) {   // f32 -> bf16 bits (RNE)
  bf h = __float2bfloat16(f);
  short s;
  __builtin_memcpy(&s, &h, 2);
  return s;
}
__device__ __forceinline__ s8b cvt8(const float* __restrict__ p) {
  float4 v0 = *(const float4*)p;
  float4 v1 = *(const float4*)(p + 4);
  s8b r;
  r[0] = f2bs(v0.x); r[1] = f2bs(v0.y); r[2] = f2bs(v0.z); r[3] = f2bs(v0.w);
  r[4] = f2bs(v1.x); r[5] = f2bs(v1.y); r[6] = f2bs(v1.z); r[7] = f2bs(v1.w);
  return r;
}
__device__ __forceinline__ s4b cvt4(float4 v) {
  s4b r;
  r[0] = f2bs(v.x); r[1] = f2bs(v.y); r[2] = f2bs(v.z); r[3] = f2bs(v.w);
  return r;
}

// ---------------------------------------------------------------------------
// Kernel 0: prep — f32->bf16 conversions + embedding gather.
// ---------------------------------------------------------------------------
__global__ __launch_bounds__(256) void prep(
    const float* __restrict__ Wihf, const float* __restrict__ Wihb,
    const float* __restrict__ Whhb, const float* __restrict__ Whhf,
    const float* __restrict__ emb, const int* __restrict__ x,
    short* __restrict__ wihfB, short* __restrict__ wihbB,
    short* __restrict__ whhbB, short* __restrict__ whhfB,
    short* __restrict__ embT)
{
  const int gid = blockIdx.x * 256 + threadIdx.x;
  const int stride = gridDim.x * 256;
  for (int i = gid; i < 131072; i += stride)       // 2048*256 / 4
    ((s4b*)wihfB)[i] = cvt4(((const float4*)Wihf)[i]);
  for (int i = gid; i < 131072; i += stride)
    ((s4b*)wihbB)[i] = cvt4(((const float4*)Wihb)[i]);
  for (int i = gid; i < 262144; i += stride)       // 2048*512 / 4
    ((s4b*)whhbB)[i] = cvt4(((const float4*)Whhb)[i]);
  for (int i = gid; i < 262144; i += stride)
    ((s4b*)whhfB)[i] = cvt4(((const float4*)Whhf)[i]);
  for (int i = gid; i < 8192; i += stride) {       // 128*256 / 4
    const int t = i >> 6, k = (i & 63) << 2;
    ((s4b*)embT)[i] = cvt4(*(const float4*)(emb + x[t] * 256 + k));
  }
}

// ---------------------------------------------------------------------------
// Kernel 1: gx precompute (both directions). 128x2048, K=256 GEMM each.
// Forward output linear [m][2048]; backward output gate-interleaved
// [m][unit][4].
// ---------------------------------------------------------------------------
__global__ __launch_bounds__(256) void gx_gemm(
    const short* __restrict__ embT,
    const short* __restrict__ WfB, const short* __restrict__ WbB,
    const float* __restrict__ bif, const float* __restrict__ bhf,
    const float* __restrict__ bib, const float* __restrict__ bhb,
    float* __restrict__ gxF, float* __restrict__ gxeB)
{
  const int tid  = threadIdx.x;
  const int nb   = blockIdx.x & 15;
  const int mat  = blockIdx.x >> 4;
  const short* W = mat ? WbB : WfB;
  const float* bi = mat ? bib : bif;
  const float* bh = mat ? bhb : bhf;
  float* out     = mat ? gxeB : gxF;

  const int wv = tid >> 6, lane = tid & 63, quad = lane >> 4, l16 = lane & 15;
  const int wm = wv >> 1, wn = wv & 1;
  const int m0 = wm * 64;
  const int n0 = nb * 128 + wn * 64;

  f4 acc[4][4];
  #pragma unroll
  for (int i = 0; i < 4; ++i)
    #pragma unroll
    for (int j = 0; j < 4; ++j) { acc[i][j][0]=0.f; acc[i][j][1]=0.f; acc[i][j][2]=0.f; acc[i][j][3]=0.f; }

  #pragma unroll
  for (int kt = 0; kt < 8; ++kt) {
    const int k = kt * 32 + quad * 8;
    s8b a[4], bb[4];
    #pragma unroll
    for (int mt = 0; mt < 4; ++mt) a[mt]  = *(const s8b*)(embT + (m0 + mt * 16 + l16) * 256 + k);
    #pragma unroll
    for (int nt = 0; nt < 4; ++nt) bb[nt] = *(const s8b*)(W + (n0 + nt * 16 + l16) * 256 + k);
    #pragma unroll
    for (int mt = 0; mt < 4; ++mt)
      #pragma unroll
      for (int nt = 0; nt < 4; ++nt)
        acc[mt][nt] = MFMA16(a[mt], bb[nt], acc[mt][nt]);
  }

  #pragma unroll
  for (int nt = 0; nt < 4; ++nt) {
    const int n = n0 + nt * 16 + l16;
    const float bias = bi[n] + bh[n];
    #pragma unroll
    for (int mt = 0; mt < 4; ++mt)
      #pragma unroll
      for (int r = 0; r < 4; ++r) {
        const int m = m0 + mt * 16 + quad * 4 + r;
        if (mat) out[m * 2048 + ((n & 511) << 2) + (n >> 9)] = acc[mt][nt][r] + bias;
        else     out[m * 2048 + n] = acc[mt][nt][r] + bias;
      }
  }
}

// ---------------------------------------------------------------------------
// Kernel 2: persistent diagonal LSTM (32 blocks x 256). Block b owns hidden
// units [16b,16b+16). Loop working set in LDS/registers (immune to the
// per-step L2 invalidation): wB in LDS (swizzled), wF in regs, gx in LDS.
// ---------------------------------------------------------------------------
__global__ __launch_bounds__(256, 1) void lstm_diag(
    const short* __restrict__ WhhFb, const short* __restrict__ WhhB,
    const float* __restrict__ gxF, const float* __restrict__ gxeB,
    bf* __restrict__ hS0, bf* __restrict__ hS1,
    bf* __restrict__ hf0, bf* __restrict__ hf1,
    bf* __restrict__ hfOut, bf* __restrict__ hbOut,
    int* __restrict__ flags)
{
  const int tid  = threadIdx.x;
  const int blk  = blockIdx.x;
  const int u0   = blk << 4;
  const int wv   = tid >> 6;
  const int lane = tid & 63;
  const int quad = lane >> 4;
  const int l16  = lane & 15;

  __shared__ __align__(16) short wBL[4 * 16 * 512];   // 64 KB backward weights
  __shared__ __align__(16) float gxFL[127 * 64];      // 32.5 KB fwd gx slice
  __shared__ __align__(16) float gxBL[128 * 64];      // 32 KB bwd gx slice
  __shared__ __align__(16) bf    hfL[512];
  __shared__ float gatesF[64];
  __shared__ float cFs[16];
  if (tid < 16) cFs[tid] = 0.f;

  // ---- stage backward weights into LDS, XOR-swizzled ----
  // wBL row rwb=(g<<4)+u (64 rows x 1KB); byte col ^= (u&7)<<4.
  for (int c = tid; c < 4096; c += 256) {            // 16B chunks
    const int rwb = c >> 6, k8 = c & 63;
    const int g = rwb >> 4, u = rwb & 15;
    const int dst = (rwb << 10) + ((k8 << 4) ^ ((u & 7) << 4));
    *(s8b*)((char*)wBL + dst) =
        *(const s8b*)(WhhB + (((g << 9) + u0 + u) << 9) + (k8 << 3));
  }
  // ---- stage gx slices into LDS ----
  for (int i = tid; i < 127 * 64; i += 256) {        // [s][g*16+u]
    const int s_ = i >> 6, g = (i >> 4) & 3, u = i & 15;
    gxFL[i] = gxF[(s_ << 11) + (g << 9) + u0 + u];
  }
  for (int i = tid; i < 128 * 64; i += 256)          // [j][u*4+g]
    gxBL[i] = gxeB[((i >> 6) << 11) + (u0 << 2) + (i & 63)];

  // ---- forward weight frags in registers (64 VGPR/lane) ----
  const short* bF = WhhFb + (((wv << 9) + u0 + l16) << 9) + (quad << 3);
  s8b wF[16];
  #pragma unroll
  for (int kt = 0; kt < 16; ++kt) wF[kt] = *(const s8b*)(bF + (kt << 5));

  float cB[8];
  #pragma unroll
  for (int i = 0; i < 8; ++i) cB[i] = 0.f;

  const int mbase0 = wv << 5;
  __syncthreads();   // LDS staging complete

  for (int s = 0; s < 127; ++s) {
    const bf* hRd  = (s & 1) ? hS0 : hS1;
    bf*       hWr  = (s & 1) ? hS1 : hS0;
    const bf* hfRd = (s & 1) ? hf0 : hf1;
    bf*       hfWr = (s & 1) ? hf1 : hf0;

    // stage forward h into LDS (256 threads x 4B = 1KB)
    ((uint*)hfL)[tid] = ((const uint*)hfRd)[tid];
    __syncthreads();   // hfL ready

    // ---- forward: gates(gate=wv, units u0..u0+15) via M=1 MFMA ----
    {
      f4 accF; accF[0] = 0.f; accF[1] = 0.f; accF[2] = 0.f; accF[3] = 0.f;
      const s8b z = {0, 0, 0, 0, 0, 0, 0, 0};
      #pragma unroll
      for (int kt = 0; kt < 16; ++kt) {
        const s8b h8 = *(const s8b*)((const short*)hfL + (kt << 5) + (quad << 3));
        const s8b a  = (l16 == 0) ? h8 : z;      // A row 0 = hf, rows 1..15 = 0
        accF = MFMA16(a, wF[kt], accF);
      }
      if (lane < 16) gatesF[(wv << 4) + lane] = accF[0] + gxFL[(s << 6) + (wv << 4) + lane];
    }

    // ---- backward batched GEMM: rows [mbase0, mbase0+32) ----
    const bool act1 = (mbase0 + 31 >= s);
    const bool act0 = (mbase0 + 15 >= s);
    if (act1) {
      f4 acc[2][4];
      #pragma unroll
      for (int h = 0; h < 2; ++h)
        #pragma unroll
        for (int g = 0; g < 4; ++g) { acc[h][g][0]=0.f; acc[h][g][1]=0.f; acc[h][g][2]=0.f; acc[h][g][3]=0.f; }
      const bf* aP0 = hRd + ((mbase0 + l16) << 9) + (quad << 3);
      const char* wb = (const char*)wBL + (l16 << 10);
      #pragma unroll
      for (int kt = 0; kt < 16; ++kt) {
        const int colsw = ((kt << 6) + (quad << 4)) ^ ((l16 & 7) << 4);
        const s8b b0 = *(const s8b*)(wb + colsw);
        const s8b b1 = *(const s8b*)(wb + (1 << 14) + colsw);
        const s8b b2 = *(const s8b*)(wb + (2 << 14) + colsw);
        const s8b b3 = *(const s8b*)(wb + (3 << 14) + colsw);
        const s8b a1 = *(const s8b*)(aP0 + (16 << 9) + (kt << 5));
        if (act0) {
          const s8b a0 = *(const s8b*)(aP0 + (kt << 5));
          acc[0][0] = MFMA16(a0, b0, acc[0][0]);
          acc[0][1] = MFMA16(a0, b1, acc[0][1]);
          acc[0][2] = MFMA16(a0, b2, acc[0][2]);
          acc[0][3] = MFMA16(a0, b3, acc[0][3]);
        }
        acc[1][0] = MFMA16(a1, b0, acc[1][0]);
        acc[1][1] = MFMA16(a1, b1, acc[1][1]);
        acc[1][2] = MFMA16(a1, b2, acc[1][2]);
        acc[1][3] = MFMA16(a1, b3, acc[1][3]);
      }
      #pragma unroll
      for (int h = 0; h < 2; ++h) {
        if (h == 0 && !act0) continue;
        const int mb = mbase0 + (h << 4);
        #pragma unroll
        for (int r = 0; r < 4; ++r) {
          const int m = mb + (quad << 2) + r;
          if (m >= s && m <= 126) {
            const float4 gv = *(const float4*)(gxBL + ((m - s) << 6) + (l16 << 2));
            const float gi = acc[h][0][r] + gv.x;
            const float gf = acc[h][1][r] + gv.y;
            const float gg = acc[h][2][r] + gv.z;
            const float go = acc[h][3][r] + gv.w;
            const float ii = sigm(gi), ff = sigm(gf);
            const float g2 = tanh_(gg), oo = sigm(go);
            const int ci = (h << 2) + r;
            const float cn = ff * cB[ci] + ii * g2;
            cB[ci] = cn;
            const bf hn = __float2bfloat16(oo * tanh_(cn));
            const int idx = (m << 9) + u0 + l16;
            if (m > s) hWr[idx] = hn;
            else       hbOut[idx] = hn;                // m == s: finalized
          }
        }
      }
    }

    __syncthreads();   // gatesF ready
    if (tid < 16) {
      const float gi = gatesF[tid], gf = gatesF[16 + tid];
      const float gg = gatesF[32 + tid], go = gatesF[48 + tid];
      const float ii = sigm(gi), ff = sigm(gf), g2 = tanh_(gg), oo = sigm(go);
      const float cn = ff * cFs[tid] + ii * g2;
      cFs[tid] = cn;
      const bf h16 = __float2bfloat16(oo * tanh_(cn));
      hfWr[u0 + tid] = h16;
      hfOut[(s << 9) + u0 + tid] = h16;
    }

    // ---- grid barrier: distributed flags (proven R3 form) ----
    __syncthreads();
    if (tid == 0) {
      __threadfence();
      __hip_atomic_store(flags + (blk << 5), s + 1, __ATOMIC_RELEASE,
                         __HIP_MEMORY_SCOPE_AGENT);
    }
    if (tid < GRID_LSTM) {
      while (__hip_atomic_load(flags + (tid << 5), __ATOMIC_ACQUIRE,
                               __HIP_MEMORY_SCOPE_AGENT) < s + 1)
        __builtin_amdgcn_s_sleep(1);
    }
    __syncthreads();
  }
}

// ---------------------------------------------------------------------------
// Kernel 3: FC (all 127 rows). A = hfO/hbO bf16; B = fc_w f32 streamed once.
// Rows 3..126 stored immediately; rows 0..2 (whose output bytes ARE hfO/hbO)
// held in acc across a one-shot 250-block grid barrier (ensuring all blocks
// finished READING hfO/hbO), then stored. fflags: 250 x 128B lines in row-2
// free space; pre-barrier stores (m>=3) never touch them, and post-barrier
// clobber of flags can only happen after global arrival (safe).
// ---------------------------------------------------------------------------
__global__ __launch_bounds__(256) void fc_main(
    const bf* __restrict__ hfOut, const bf* __restrict__ hbOut,
    const float* __restrict__ fcw, const float* __restrict__ fcb,
    float* __restrict__ out, int* __restrict__ fflags)
{
  const int tid = threadIdx.x;
  const int wv = tid >> 6, lane = tid & 63, quad = lane >> 4, l16 = lane & 15;
  const int wm = wv >> 1, wn = wv & 1;
  const int m0 = wm * 64;
  const int n0 = blockIdx.x * 128 + wn * 64;

  f4 acc[4][4];
  #pragma unroll
  for (int i = 0; i < 4; ++i)
    #pragma unroll
    for (int j = 0; j < 4; ++j) { acc[i][j][0]=0.f; acc[i][j][1]=0.f; acc[i][j][2]=0.f; acc[i][j][3]=0.f; }

  #pragma unroll
  for (int half = 0; half < 2; ++half) {
    const bf* A = half ? hbOut : hfOut;
    #pragma unroll
    for (int kt = 0; kt < 16; ++kt) {
      const int k = kt * 32 + quad * 8;
      s8b a[4], b[4];
      #pragma unroll
      for (int mt = 0; mt < 4; ++mt) a[mt] = *(const s8b*)(A + (m0 + mt * 16 + l16) * 512 + k);
      #pragma unroll
      for (int nt = 0; nt < 4; ++nt) b[nt] = cvt8(fcw + (n0 + nt * 16 + l16) * 1024 + half * 512 + k);
      #pragma unroll
      for (int mt = 0; mt < 4; ++mt)
        #pragma unroll
        for (int nt = 0; nt < 4; ++nt)
          acc[mt][nt] = MFMA16(a[mt], b[nt], acc[mt][nt]);
    }
  }

  // ---- immediate stores: rows 3..126 ----
  #pragma unroll
  for (int nt = 0; nt < 4; ++nt) {
    const int n = n0 + nt * 16 + l16;
    const float bb = fcb[n];
    #pragma unroll
    for (int mt = 0; mt < 4; ++mt)
      #pragma unroll
      for (int r = 0; r < 4; ++r) {
        const int m = m0 + mt * 16 + quad * 4 + r;
        if (m >= 3 && m <= 126)
          out[m * 32000 + n] = acc[mt][nt][r] + bb;
      }
  }

  // ---- one-shot grid barrier: all hfO/hbO reads complete ----
  __syncthreads();
  if (tid == 0) {
    __threadfence();
    __hip_atomic_store(fflags + (blockIdx.x << 5), 1, __ATOMIC_RELEASE,
                       __HIP_MEMORY_SCOPE_AGENT);
  }
  if (tid < GRID_FC) {
    while (__hip_atomic_load(fflags + (tid << 5), __ATOMIC_ACQUIRE,
                             __HIP_MEMORY_SCOPE_AGENT) < 1)
      __builtin_amdgcn_s_sleep(1);
  }
  __syncthreads();

  // ---- deferred stores: rows 0..2 (clobber hfO/hbO region) ----
  #pragma unroll
  for (int nt = 0; nt < 4; ++nt) {
    const int n = n0 + nt * 16 + l16;
    const float bb = fcb[n];
    #pragma unroll
    for (int mt = 0; mt < 4; ++mt)
      #pragma unroll
      for (int r = 0; r < 4; ++r) {
        const int m = m0 + mt * 16 + quad * 4 + r;
        if (m < 3)
          out[m * 32000 + n] = acc[mt][nt][r] + bb;
      }
  }
}

// ---------------------------------------------------------------------------
extern "C" void kernel_launch(void* const* d_in, const int* in_sizes, int n_in,
                              void* d_out, int out_size, void* d_ws, size_t ws_size,
                              hipStream_t stream) {
  const int*   x    = (const int*)d_in[0];
  const float* emb  = (const float*)d_in[1];
  const float* Wihf = (const float*)d_in[2];
  const float* Whhf = (const float*)d_in[3];
  const float* bihf = (const float*)d_in[4];
  const float* bhhf = (const float*)d_in[5];
  const float* Wihb = (const float*)d_in[6];
  const float* Whhb = (const float*)d_in[7];
  const float* bihb = (const float*)d_in[8];
  const float* bhhb = (const float*)d_in[9];
  const float* fcw  = (const float*)d_in[10];
  const float* fcb  = (const float*)d_in[11];
  float* out = (float*)d_out;

  char* S = (char*)d_out;                 // ALL scratch lives in d_out
  bf*    hfO   = (bf*)(S + 0);
  bf*    hbO   = (bf*)(S + 131072);
  bf*    hS0   = (bf*)(S + 262144);
  bf*    hS1   = (bf*)(S + 393216);
  float* gxF   = (float*)(S + 524288);
  float* gxeB  = (float*)(S + 1572864);
  bf*    hfb0  = (bf*)(S + 2621696);
  bf*    hfb1  = (bf*)(S + 2623744);
  short* wihfB = (short*)(S + 2625792);
  short* wihbB = (short*)(S + 3674368);
  short* whhbB = (short*)(S + 4722944);
  short* embT  = (short*)(S + 6820096);
  short* whhfB = (short*)(S + 6885632);
  int*   flags = (int*)(S + 8982784);     // 32 x 128B (lstm barrier)
  int*   fflags = (int*)(S + 262144);     // 250 x 128B (fc barrier, reuses hS0)

  // zero hS0/hS1 + gx + hf ping-pong, and the lstm flag lines
  hipMemsetAsync(S + 262144, 0, 2625792 - 262144, stream);
  hipMemsetAsync(S + 8982784, 0, 4096, stream);

  hipLaunchKernelGGL(prep, dim3(256), dim3(256), 0, stream,
                     Wihf, Wihb, Whhb, Whhf, emb, x, wihfB, wihbB, whhbB, whhfB, embT);
  hipLaunchKernelGGL(gx_gemm, dim3(32), dim3(256), 0, stream,
                     embT, wihfB, wihbB, bihf, bhhf, bihb, bhhb, gxF, gxeB);
  hipLaunchKernelGGL(lstm_diag, dim3(GRID_LSTM), dim3(256), 0, stream,
                     whhfB, whhbB, gxF, gxeB, hS0, hS1, hfb0, hfb1, hfO, hbO, flags);
  // fc barrier flags (hS0 region is dead after lstm)
  hipMemsetAsync(S + 262144, 0, GRID_FC * 128, stream);
  hipLaunchKernelGGL(fc_main, dim3(GRID_FC), dim3(256), 0, stream,
                     hfO, hbO, fcw, fcb, out, fflags);
}

// Round 5
// 1520.092 us; speedup vs baseline: 2.4149x; 1.0412x over previous
//
#include <hip/hip_runtime.h>
#include <hip/hip_bf16.h>

// PrefixBLSTM: diagonal-batched bidirectional prefix LSTM + FC head.
// L=128 tokens, T=127 outputs, E=256, H=512, 4H=2048, V=32000.
// ALL float inputs are FLOAT32; output f32 (threshold 2.060547e-3).
//
// Round-5 (prev best 1583 us; lstm_diag=1210 us @ 9.5 us/step, fc ~300 us):
//  - fc_main REWRITE: B-tile (128 n-rows x 32 k) staged into LDS per K-chunk
//    with fully-coalesced float4 loads (8 lanes = one 128B line), f32->bf16
//    converted ONCE during staging, double-buffered; MFMA frags via aligned
//    ds_read_b128 (row stride 80B, conflict-light). Was: per-frag scattered
//    32B f32 loads at 4KB stride + 32 cvt/lane/kt -> ~300us for a 131MB
//    stream. Target 50-90us.
//  - lstm_diag: redundant __threadfence before the RELEASE flag store
//    removed (release store already drains+wbl2; the threadfence added a
//    second wbl2 PLUS a useless inv per step). hbOut/hfOut staging stores
//    (consumed only post-kernel) deferred until AFTER the flag release so
//    they overlap the remote flag-propagation window.
//  - everything else byte-identical to the proven R4 kernel.
//
// Scratch in d_out (16,256,000 B):
//   [0,       131072)  hfO   : hf rows 0..127 bf16
//   [131072,  262144)  hbO   : hb rows 0..127 bf16
//   [262144,  393216)  hS0   : backward-h dbuf A (zeroed) / later fc flags
//   [393216,  524288)  hS1   : backward-h dbuf B (zeroed)
//   [524288, 1572864)  gxF   : f32 128x2048 (linear)
//   [1572864,2621440)  gxeB  : f32 128x512x4 gate-interleaved
//   [2621696,2623744)  hf0   : bf16 fwd-h ping (zeroed)
//   [2623744,2625792)  hf1   : bf16 fwd-h pong (zeroed)
//   [2625792,3674368)  WihF bf16 2048x256
//   [3674368,4722944)  WihB bf16 2048x256
//   [4722944,6820096)  WhhB bf16 2048x512
//   [6820096,6885632)  embT bf16 128x256
//   [6885632,8982784)  WhhF bf16 2048x512
//   [8982784,8986880)  flags: 32 x 128B lstm barrier flags (zeroed)
//
// Phases: memset -> prep -> gx_gemm -> lstm_diag -> memset(fc flags)
//         -> fc_main (all rows; internal grid barrier for rows 0..2)

typedef __hip_bfloat16 bf;
typedef __attribute__((ext_vector_type(8))) short s8b;   // 8 bf16 (MFMA A/B frag)
typedef __attribute__((ext_vector_type(4))) short s4b;   // 4 bf16
typedef __attribute__((ext_vector_type(4))) float f4;    // MFMA C/D frag

#define MFMA16(a, b, c) __builtin_amdgcn_mfma_f32_16x16x32_bf16((a), (b), (c), 0, 0, 0)
#define GRID_LSTM 32
#define GRID_FC   250

__device__ __forceinline__ float sigm(float x) { return 1.f / (1.f + __expf(-x)); }
__device__ __forceinline__ float tanh_(float x) { return 1.f - 2.f / (__expf(2.f * x) + 1.f); }

__device__ __forceinline__ short f2bs(float f) {   // f32 -> bf16 bits (RNE)
  bf h = __float2bfloat16(f);
  short s;
  __builtin_memcpy(&s, &h, 2);
  return s;
}
__device__ __forceinline__ s4b cvt4(float4 v) {
  s4b r;
  r[0] = f2bs(v.x); r[1] = f2bs(v.y); r[2] = f2bs(v.z); r[3] = f2bs(v.w);
  return r;
}

// ---------------------------------------------------------------------------
// Kernel 0: prep — f32->bf16 conversions + embedding gather.
// ---------------------------------------------------------------------------
__global__ __launch_bounds__(256) void prep(
    const float* __restrict__ Wihf, const float* __restrict__ Wihb,
    const float* __restrict__ Whhb, const float* __restrict__ Whhf,
    const float* __restrict__ emb, const int* __restrict__ x,
    short* __restrict__ wihfB, short* __restrict__ wihbB,
    short* __restrict__ whhbB, short* __restrict__ whhfB,
    short* __restrict__ embT)
{
  const int gid = blockIdx.x * 256 + threadIdx.x;
  const int stride = gridDim.x * 256;
  for (int i = gid; i < 131072; i += stride)       // 2048*256 / 4
    ((s4b*)wihfB)[i] = cvt4(((const float4*)Wihf)[i]);
  for (int i = gid; i < 131072; i += stride)
    ((s4b*)wihbB)[i] = cvt4(((const float4*)Wihb)[i]);
  for (int i = gid; i < 262144; i += stride)       // 2048*512 / 4
    ((s4b*)whhbB)[i] = cvt4(((const float4*)Whhb)[i]);
  for (int i = gid; i < 262144; i += stride)
    ((s4b*)whhfB)[i] = cvt4(((const float4*)Whhf)[i]);
  for (int i = gid; i < 8192; i += stride) {       // 128*256 / 4
    const int t = i >> 6, k = (i & 63) << 2;
    ((s4b*)embT)[i] = cvt4(*(const float4*)(emb + x[t] * 256 + k));
  }
}

// ---------------------------------------------------------------------------
// Kernel 1: gx precompute (both directions). 128x2048, K=256 GEMM each.
// Forward output linear [m][2048]; backward output gate-interleaved
// [m][unit][4].
// ---------------------------------------------------------------------------
__global__ __launch_bounds__(256) void gx_gemm(
    const short* __restrict__ embT,
    const short* __restrict__ WfB, const short* __restrict__ WbB,
    const float* __restrict__ bif, const float* __restrict__ bhf,
    const float* __restrict__ bib, const float* __restrict__ bhb,
    float* __restrict__ gxF, float* __restrict__ gxeB)
{
  const int tid  = threadIdx.x;
  const int nb   = blockIdx.x & 15;
  const int mat  = blockIdx.x >> 4;
  const short* W = mat ? WbB : WfB;
  const float* bi = mat ? bib : bif;
  const float* bh = mat ? bhb : bhf;
  float* out     = mat ? gxeB : gxF;

  const int wv = tid >> 6, lane = tid & 63, quad = lane >> 4, l16 = lane & 15;
  const int wm = wv >> 1, wn = wv & 1;
  const int m0 = wm * 64;
  const int n0 = nb * 128 + wn * 64;

  f4 acc[4][4];
  #pragma unroll
  for (int i = 0; i < 4; ++i)
    #pragma unroll
    for (int j = 0; j < 4; ++j) { acc[i][j][0]=0.f; acc[i][j][1]=0.f; acc[i][j][2]=0.f; acc[i][j][3]=0.f; }

  #pragma unroll
  for (int kt = 0; kt < 8; ++kt) {
    const int k = kt * 32 + quad * 8;
    s8b a[4], bb[4];
    #pragma unroll
    for (int mt = 0; mt < 4; ++mt) a[mt]  = *(const s8b*)(embT + (m0 + mt * 16 + l16) * 256 + k);
    #pragma unroll
    for (int nt = 0; nt < 4; ++nt) bb[nt] = *(const s8b*)(W + (n0 + nt * 16 + l16) * 256 + k);
    #pragma unroll
    for (int mt = 0; mt < 4; ++mt)
      #pragma unroll
      for (int nt = 0; nt < 4; ++nt)
        acc[mt][nt] = MFMA16(a[mt], bb[nt], acc[mt][nt]);
  }

  #pragma unroll
  for (int nt = 0; nt < 4; ++nt) {
    const int n = n0 + nt * 16 + l16;
    const float bias = bi[n] + bh[n];
    #pragma unroll
    for (int mt = 0; mt < 4; ++mt)
      #pragma unroll
      for (int r = 0; r < 4; ++r) {
        const int m = m0 + mt * 16 + quad * 4 + r;
        if (mat) out[m * 2048 + ((n & 511) << 2) + (n >> 9)] = acc[mt][nt][r] + bias;
        else     out[m * 2048 + n] = acc[mt][nt][r] + bias;
      }
  }
}

// ---------------------------------------------------------------------------
// Kernel 2: persistent diagonal LSTM (32 blocks x 256). Block b owns hidden
// units [16b,16b+16). Loop working set in LDS/registers (immune to the
// per-step L2 invalidation): wB in LDS (swizzled), wF in regs, gx in LDS.
// ---------------------------------------------------------------------------
__global__ __launch_bounds__(256, 1) void lstm_diag(
    const short* __restrict__ WhhFb, const short* __restrict__ WhhB,
    const float* __restrict__ gxF, const float* __restrict__ gxeB,
    bf* __restrict__ hS0, bf* __restrict__ hS1,
    bf* __restrict__ hf0, bf* __restrict__ hf1,
    bf* __restrict__ hfOut, bf* __restrict__ hbOut,
    int* __restrict__ flags)
{
  const int tid  = threadIdx.x;
  const int blk  = blockIdx.x;
  const int u0   = blk << 4;
  const int wv   = tid >> 6;
  const int lane = tid & 63;
  const int quad = lane >> 4;
  const int l16  = lane & 15;

  __shared__ __align__(16) short wBL[4 * 16 * 512];   // 64 KB backward weights
  __shared__ __align__(16) float gxFL[127 * 64];      // 32.5 KB fwd gx slice
  __shared__ __align__(16) float gxBL[128 * 64];      // 32 KB bwd gx slice
  __shared__ __align__(16) bf    hfL[512];
  __shared__ float gatesF[64];
  __shared__ float cFs[16];
  if (tid < 16) cFs[tid] = 0.f;

  // ---- stage backward weights into LDS, XOR-swizzled ----
  for (int c = tid; c < 4096; c += 256) {            // 16B chunks
    const int rwb = c >> 6, k8 = c & 63;
    const int g = rwb >> 4, u = rwb & 15;
    const int dst = (rwb << 10) + ((k8 << 4) ^ ((u & 7) << 4));
    *(s8b*)((char*)wBL + dst) =
        *(const s8b*)(WhhB + (((g << 9) + u0 + u) << 9) + (k8 << 3));
  }
  // ---- stage gx slices into LDS ----
  for (int i = tid; i < 127 * 64; i += 256) {        // [s][g*16+u]
    const int s_ = i >> 6, g = (i >> 4) & 3, u = i & 15;
    gxFL[i] = gxF[(s_ << 11) + (g << 9) + u0 + u];
  }
  for (int i = tid; i < 128 * 64; i += 256)          // [j][u*4+g]
    gxBL[i] = gxeB[((i >> 6) << 11) + (u0 << 2) + (i & 63)];

  // ---- forward weight frags in registers (64 VGPR/lane) ----
  const short* bF = WhhFb + (((wv << 9) + u0 + l16) << 9) + (quad << 3);
  s8b wF[16];
  #pragma unroll
  for (int kt = 0; kt < 16; ++kt) wF[kt] = *(const s8b*)(bF + (kt << 5));

  float cB[8];
  #pragma unroll
  for (int i = 0; i < 8; ++i) cB[i] = 0.f;

  const int mbase0 = wv << 5;
  __syncthreads();   // LDS staging complete

  for (int s = 0; s < 127; ++s) {
    const bf* hRd  = (s & 1) ? hS0 : hS1;
    bf*       hWr  = (s & 1) ? hS1 : hS0;
    const bf* hfRd = (s & 1) ? hf0 : hf1;
    bf*       hfWr = (s & 1) ? hf1 : hf0;

    // stage forward h into LDS (256 threads x 4B = 1KB)
    ((uint*)hfL)[tid] = ((const uint*)hfRd)[tid];
    __syncthreads();   // hfL ready

    // ---- forward: gates(gate=wv, units u0..u0+15) via M=1 MFMA ----
    {
      f4 accF; accF[0] = 0.f; accF[1] = 0.f; accF[2] = 0.f; accF[3] = 0.f;
      const s8b z = {0, 0, 0, 0, 0, 0, 0, 0};
      #pragma unroll
      for (int kt = 0; kt < 16; ++kt) {
        const s8b h8 = *(const s8b*)((const short*)hfL + (kt << 5) + (quad << 3));
        const s8b a  = (l16 == 0) ? h8 : z;      // A row 0 = hf, rows 1..15 = 0
        accF = MFMA16(a, wF[kt], accF);
      }
      if (lane < 16) gatesF[(wv << 4) + lane] = accF[0] + gxFL[(s << 6) + (wv << 4) + lane];
    }

    // ---- backward batched GEMM: rows [mbase0, mbase0+32) ----
    int pendIdx = -1;                 // deferred hbOut store (m == s row)
    bf  pendHn  = __float2bfloat16(0.f);
    const bool act1 = (mbase0 + 31 >= s);
    const bool act0 = (mbase0 + 15 >= s);
    if (act1) {
      f4 acc[2][4];
      #pragma unroll
      for (int h = 0; h < 2; ++h)
        #pragma unroll
        for (int g = 0; g < 4; ++g) { acc[h][g][0]=0.f; acc[h][g][1]=0.f; acc[h][g][2]=0.f; acc[h][g][3]=0.f; }
      const bf* aP0 = hRd + ((mbase0 + l16) << 9) + (quad << 3);
      const char* wb = (const char*)wBL + (l16 << 10);
      #pragma unroll
      for (int kt = 0; kt < 16; ++kt) {
        const int colsw = ((kt << 6) + (quad << 4)) ^ ((l16 & 7) << 4);
        const s8b b0 = *(const s8b*)(wb + colsw);
        const s8b b1 = *(const s8b*)(wb + (1 << 14) + colsw);
        const s8b b2 = *(const s8b*)(wb + (2 << 14) + colsw);
        const s8b b3 = *(const s8b*)(wb + (3 << 14) + colsw);
        const s8b a1 = *(const s8b*)(aP0 + (16 << 9) + (kt << 5));
        if (act0) {
          const s8b a0 = *(const s8b*)(aP0 + (kt << 5));
          acc[0][0] = MFMA16(a0, b0, acc[0][0]);
          acc[0][1] = MFMA16(a0, b1, acc[0][1]);
          acc[0][2] = MFMA16(a0, b2, acc[0][2]);
          acc[0][3] = MFMA16(a0, b3, acc[0][3]);
        }
        acc[1][0] = MFMA16(a1, b0, acc[1][0]);
        acc[1][1] = MFMA16(a1, b1, acc[1][1]);
        acc[1][2] = MFMA16(a1, b2, acc[1][2]);
        acc[1][3] = MFMA16(a1, b3, acc[1][3]);
      }
      #pragma unroll
      for (int h = 0; h < 2; ++h) {
        if (h == 0 && !act0) continue;
        const int mb = mbase0 + (h << 4);
        #pragma unroll
        for (int r = 0; r < 4; ++r) {
          const int m = mb + (quad << 2) + r;
          if (m >= s && m <= 126) {
            const float4 gv = *(const float4*)(gxBL + ((m - s) << 6) + (l16 << 2));
            const float gi = acc[h][0][r] + gv.x;
            const float gf = acc[h][1][r] + gv.y;
            const float gg = acc[h][2][r] + gv.z;
            const float go = acc[h][3][r] + gv.w;
            const float ii = sigm(gi), ff = sigm(gf);
            const float g2 = tanh_(gg), oo = sigm(go);
            const int ci = (h << 2) + r;
            const float cn = ff * cB[ci] + ii * g2;
            cB[ci] = cn;
            const bf hn = __float2bfloat16(oo * tanh_(cn));
            const int idx = (m << 9) + u0 + l16;
            if (m > s) hWr[idx] = hn;
            else       { pendHn = hn; pendIdx = idx; }   // m == s: deferred
          }
        }
      }
    }

    __syncthreads();   // gatesF ready
    bf hfPend = __float2bfloat16(0.f);
    if (tid < 16) {
      const float gi = gatesF[tid], gf = gatesF[16 + tid];
      const float gg = gatesF[32 + tid], go = gatesF[48 + tid];
      const float ii = sigm(gi), ff = sigm(gf), g2 = tanh_(gg), oo = sigm(go);
      const float cn = ff * cFs[tid] + ii * g2;
      cFs[tid] = cn;
      const bf h16 = __float2bfloat16(oo * tanh_(cn));
      hfWr[u0 + tid] = h16;
      hfPend = h16;
    }

    // ---- grid barrier: distributed flags. The RELEASE store itself drains
    // this wave's stores + writes back L2 (all other waves drained by the
    // preceding __syncthreads), so no explicit __threadfence is needed. ----
    __syncthreads();
    if (tid == 0) {
      __hip_atomic_store(flags + (blk << 5), s + 1, __ATOMIC_RELEASE,
                         __HIP_MEMORY_SCOPE_AGENT);
    }
    // deferred output staging (consumed only post-kernel) — overlaps with
    // remote flag propagation
    if (tid < 16) hfOut[(s << 9) + u0 + tid] = hfPend;
    if (pendIdx >= 0) hbOut[pendIdx] = pendHn;
    if (tid < GRID_LSTM) {
      while (__hip_atomic_load(flags + (tid << 5), __ATOMIC_ACQUIRE,
                               __HIP_MEMORY_SCOPE_AGENT) < s + 1)
        __builtin_amdgcn_s_sleep(1);
    }
    __syncthreads();
  }
}

// ---------------------------------------------------------------------------
// Kernel 3: FC (all 127 rows). A = hfO/hbO bf16 (global, L2-hot); B = fc_w
// f32 streamed ONCE, coalesced through LDS (converted to bf16 during
// staging, double-buffered). Rows 3..126 stored immediately; rows 0..2
// (whose output bytes ARE hfO/hbO) held in acc across a one-shot 250-block
// grid barrier, then stored.
// ---------------------------------------------------------------------------
__global__ __launch_bounds__(256) void fc_main(
    const bf* __restrict__ hfOut, const bf* __restrict__ hbOut,
    const float* __restrict__ fcw, const float* __restrict__ fcb,
    float* __restrict__ out, int* __restrict__ fflags)
{
  // B-tile: [buf][n(128)][40 shorts (32 used, 80B stride: 16B-aligned,
  // bank-period 8 -> only free 2-way conflicts on ds_read_b128)]
  __shared__ __align__(16) short Bs[2][128 * 40];

  const int tid = threadIdx.x;
  const int wv = tid >> 6, lane = tid & 63, quad = lane >> 4, l16 = lane & 15;
  const int wm = wv >> 1, wn = wv & 1;
  const int m0 = wm * 64;
  const int nB = blockIdx.x * 128;        // block n-base
  const int n0 = nB + wn * 64;            // wave n-base

  const int sr = tid >> 3;                // staging row within pass (0..31)
  const int sc = (tid & 7) << 2;          // staging f32 col (0,4,..,28)

  f4 acc[4][4];
  #pragma unroll
  for (int i = 0; i < 4; ++i)
    #pragma unroll
    for (int j = 0; j < 4; ++j) { acc[i][j][0]=0.f; acc[i][j][1]=0.f; acc[i][j][2]=0.f; acc[i][j][3]=0.f; }

  // stage K-chunk kt (32 f32 cols) of rows nB..nB+127 into Bs[buf] as bf16
  #define STAGE_B(ktv, bufv)                                                  \
    {                                                                         \
      const int k_ = (ktv) << 5;                                              \
      _Pragma("unroll")                                                       \
      for (int p = 0; p < 4; ++p) {                                           \
        const int r_ = sr + p * 32;                                           \
        float4 v_ = *(const float4*)(fcw + (nB + r_) * 1024 + k_ + sc);       \
        *(s4b*)(&Bs[bufv][r_ * 40 + sc]) = cvt4(v_);                          \
      }                                                                       \
    }

  STAGE_B(0, 0)
  __syncthreads();

  for (int kt = 0; kt < 32; ++kt) {
    const int buf = kt & 1;
    if (kt < 31) STAGE_B(kt + 1, buf ^ 1)

    const int k  = kt << 5;
    const bf* A  = (kt < 16) ? hfOut : hbOut;
    const int ka = (k & 511) + (quad << 3);
    s8b a[4], b[4];
    #pragma unroll
    for (int mt = 0; mt < 4; ++mt)
      a[mt] = *(const s8b*)(A + (m0 + mt * 16 + l16) * 512 + ka);
    #pragma unroll
    for (int nt = 0; nt < 4; ++nt)
      b[nt] = *(const s8b*)(&Bs[buf][(wn * 64 + nt * 16 + l16) * 40 + (quad << 3)]);
    #pragma unroll
    for (int mt = 0; mt < 4; ++mt)
      #pragma unroll
      for (int nt = 0; nt < 4; ++nt)
        acc[mt][nt] = MFMA16(a[mt], b[nt], acc[mt][nt]);
    __syncthreads();
  }
  #undef STAGE_B

  // ---- immediate stores: rows 3..126 ----
  #pragma unroll
  for (int nt = 0; nt < 4; ++nt) {
    const int n = n0 + nt * 16 + l16;
    const float bb = fcb[n];
    #pragma unroll
    for (int mt = 0; mt < 4; ++mt)
      #pragma unroll
      for (int r = 0; r < 4; ++r) {
        const int m = m0 + mt * 16 + quad * 4 + r;
        if (m >= 3 && m <= 126)
          out[m * 32000 + n] = acc[mt][nt][r] + bb;
      }
  }

  // ---- one-shot grid barrier: all hfO/hbO reads complete ----
  __syncthreads();
  if (tid == 0) {
    __hip_atomic_store(fflags + (blockIdx.x << 5), 1, __ATOMIC_RELEASE,
                       __HIP_MEMORY_SCOPE_AGENT);
  }
  if (tid < GRID_FC) {
    while (__hip_atomic_load(fflags + (tid << 5), __ATOMIC_ACQUIRE,
                             __HIP_MEMORY_SCOPE_AGENT) < 1)
      __builtin_amdgcn_s_sleep(1);
  }
  __syncthreads();

  // ---- deferred stores: rows 0..2 (clobber hfO/hbO region) ----
  #pragma unroll
  for (int nt = 0; nt < 4; ++nt) {
    const int n = n0 + nt * 16 + l16;
    const float bb = fcb[n];
    #pragma unroll
    for (int mt = 0; mt < 4; ++mt)
      #pragma unroll
      for (int r = 0; r < 4; ++r) {
        const int m = m0 + mt * 16 + quad * 4 + r;
        if (m < 3)
          out[m * 32000 + n] = acc[mt][nt][r] + bb;
      }
  }
}

// ---------------------------------------------------------------------------
extern "C" void kernel_launch(void* const* d_in, const int* in_sizes, int n_in,
                              void* d_out, int out_size, void* d_ws, size_t ws_size,
                              hipStream_t stream) {
  const int*   x    = (const int*)d_in[0];
  const float* emb  = (const float*)d_in[1];
  const float* Wihf = (const float*)d_in[2];
  const float* Whhf = (const float*)d_in[3];
  const float* bihf = (const float*)d_in[4];
  const float* bhhf = (const float*)d_in[5];
  const float* Wihb = (const float*)d_in[6];
  const float* Whhb = (const float*)d_in[7];
  const float* bihb = (const float*)d_in[8];
  const float* bhhb = (const float*)d_in[9];
  const float* fcw  = (const float*)d_in[10];
  const float* fcb  = (const float*)d_in[11];
  float* out = (float*)d_out;

  char* S = (char*)d_out;                 // ALL scratch lives in d_out
  bf*    hfO   = (bf*)(S + 0);
  bf*    hbO   = (bf*)(S + 131072);
  bf*    hS0   = (bf*)(S + 262144);
  bf*    hS1   = (bf*)(S + 393216);
  float* gxF   = (float*)(S + 524288);
  float* gxeB  = (float*)(S + 1572864);
  bf*    hfb0  = (bf*)(S + 2621696);
  bf*    hfb1  = (bf*)(S + 2623744);
  short* wihfB = (short*)(S + 2625792);
  short* wihbB = (short*)(S + 3674368);
  short* whhbB = (short*)(S + 4722944);
  short* embT  = (short*)(S + 6820096);
  short* whhfB = (short*)(S + 6885632);
  int*   flags = (int*)(S + 8982784);     // 32 x 128B (lstm barrier)
  int*   fflags = (int*)(S + 262144);     // 250 x 128B (fc barrier, reuses hS0)

  // zero hS0/hS1 + gx + hf ping-pong, and the lstm flag lines
  hipMemsetAsync(S + 262144, 0, 2625792 - 262144, stream);
  hipMemsetAsync(S + 8982784, 0, 4096, stream);

  hipLaunchKernelGGL(prep, dim3(256), dim3(256), 0, stream,
                     Wihf, Wihb, Whhb, Whhf, emb, x, wihfB, wihbB, whhbB, whhfB, embT);
  hipLaunchKernelGGL(gx_gemm, dim3(32), dim3(256), 0, stream,
                     embT, wihfB, wihbB, bihf, bhhf, bihb, bhhb, gxF, gxeB);
  hipLaunchKernelGGL(lstm_diag, dim3(GRID_LSTM), dim3(256), 0, stream,
                     whhfB, whhbB, gxF, gxeB, hS0, hS1, hfb0, hfb1, hfO, hbO, flags);
  // fc barrier flags (hS0 region is dead after lstm)
  hipMemsetAsync(S + 262144, 0, GRID_FC * 128, stream);
  hipLaunchKernelGGL(fc_main, dim3(GRID_FC), dim3(256), 0, stream,
                     hfO, hbO, fcw, fcb, out, fflags);
}